// Round 1
// baseline (1105.732 us; speedup 1.0000x reference)
//
#include <hip/hip_runtime.h>
#include <hip/hip_bf16.h>

#define NN 100000
#define EE 1250000

// ---------------- CSR build ----------------

__global__ __launch_bounds__(256) void k_zero(float* deg, int* count) {
    int i = blockIdx.x * 256 + threadIdx.x;
    if (i < NN) { deg[i] = 0.f; count[i] = 0; }
}

__global__ __launch_bounds__(256) void k_count(const int* __restrict__ ei,
                                               const float* __restrict__ ew,
                                               float* __restrict__ deg,
                                               int* __restrict__ count) {
    int e = blockIdx.x * 256 + threadIdx.x;
    if (e >= EE) return;
    int d = ei[EE + e];
    atomicAdd(&deg[d], ew[e]);
    atomicAdd(&count[d], 1);
}

__global__ __launch_bounds__(256) void k_dinv(float* __restrict__ deg_dinv,
                                              float* __restrict__ selfn) {
    int i = blockIdx.x * 256 + threadIdx.x;
    if (i >= NN) return;
    float d = deg_dinv[i] + 1.0f;   // self-loop weight 1.0 => deg always > 0
    float di = rsqrtf(d);
    deg_dinv[i] = di;
    selfn[i] = di * di;
}

__global__ __launch_bounds__(256) void k_bsum(const int* __restrict__ count, int* __restrict__ bsum) {
    __shared__ int ls[256];
    int b = blockIdx.x, tid = threadIdx.x;
    int base = b * 1024 + tid * 4;
    int s = 0;
    #pragma unroll
    for (int j = 0; j < 4; ++j) { int g = base + j; if (g < NN) s += count[g]; }
    ls[tid] = s; __syncthreads();
    for (int off = 128; off > 0; off >>= 1) {
        if (tid < off) ls[tid] += ls[tid + off];
        __syncthreads();
    }
    if (tid == 0) bsum[b] = ls[0];
}

__global__ void k_bscan(const int* __restrict__ bsum, int* __restrict__ boff, int nb) {
    if (threadIdx.x == 0 && blockIdx.x == 0) {
        int run = 0;
        for (int b = 0; b < nb; ++b) { boff[b] = run; run += bsum[b]; }
    }
}

// count[] is transformed in-place into cursor[] (exclusive prefix per element)
__global__ __launch_bounds__(256) void k_scan_out(int* __restrict__ count_cursor,
                                                  const int* __restrict__ boff,
                                                  int* __restrict__ rowptr) {
    __shared__ int ls[256];
    int b = blockIdx.x, tid = threadIdx.x;
    int base = b * 1024 + tid * 4;
    int c[4]; int s = 0;
    #pragma unroll
    for (int j = 0; j < 4; ++j) {
        int g = base + j;
        c[j] = (g < NN) ? count_cursor[g] : 0;
        s += c[j];
    }
    ls[tid] = s; __syncthreads();
    for (int off = 1; off < 256; off <<= 1) {
        int v = (tid >= off) ? ls[tid - off] : 0;
        __syncthreads();
        ls[tid] += v;
        __syncthreads();
    }
    int excl = ls[tid] - s + boff[b];
    #pragma unroll
    for (int j = 0; j < 4; ++j) {
        int g = base + j;
        if (g < NN) {
            count_cursor[g] = excl;       // cursor for fill
            rowptr[g + 1] = excl + c[j];  // inclusive => rowptr[g+1]
            excl += c[j];
        }
    }
    if (b == 0 && tid == 0) rowptr[0] = 0;
}

__global__ __launch_bounds__(256) void k_fill(const int* __restrict__ ei,
                                              const float* __restrict__ ew,
                                              const float* __restrict__ dinv,
                                              int* __restrict__ cursor,
                                              int2* __restrict__ epair) {
    int e = blockIdx.x * 256 + threadIdx.x;
    if (e >= EE) return;
    int s = ei[e];
    int d = ei[EE + e];
    float nrm = dinv[s] * ew[e] * dinv[d];
    int p = atomicAdd(&cursor[d], 1);
    epair[p] = make_int2(s, __float_as_int(nrm));
}

// ---------------- Layers ----------------

// Layer 1: H[n][c] = x[n] * W1[c]   (x is N x 1, W1 is 1 x 64)
__global__ __launch_bounds__(256) void k_layer1(const float* __restrict__ x,
                                                const float* __restrict__ W1,
                                                float* __restrict__ H) {
    int i = blockIdx.x * 256 + threadIdx.x;   // grid covers exactly N*64
    int n = i >> 6, c = i & 63;
    H[i] = x[n] * W1[c];
}

// H = relu(X + bias_prev) @ W    (X,H: N x 64 row-major; W: 64 x 64 [k][c] row-major)
__global__ __launch_bounds__(256) void gemm_bias_relu(const float* __restrict__ X,
                                                      const float* __restrict__ bias,
                                                      const float* __restrict__ W,
                                                      float* __restrict__ H) {
    __shared__ float sW[64 * 64];
    __shared__ float sX[64 * 64];
    int tid = threadIdx.x;
    int rowbase = blockIdx.x * 64;
    #pragma unroll
    for (int i = 0; i < 16; ++i) sW[tid + i * 256] = W[tid + i * 256];
    #pragma unroll
    for (int i = 0; i < 16; ++i) {
        int idx = tid + i * 256;
        int r = idx >> 6, k = idx & 63;
        int gr = rowbase + r;
        float v = 0.f;
        if (gr < NN) v = X[gr * 64 + k];
        v = fmaxf(v + bias[k], 0.f);
        sX[idx] = v;
    }
    __syncthreads();
    int c = tid & 63, rg = tid >> 6;   // wave-uniform rg => sX reads broadcast
    float acc[16];
    #pragma unroll
    for (int i = 0; i < 16; ++i) acc[i] = 0.f;
    for (int k = 0; k < 64; ++k) {
        float w = sW[k * 64 + c];
        #pragma unroll
        for (int i = 0; i < 16; ++i)
            acc[i] = fmaf(sX[(rg * 16 + i) * 64 + k], w, acc[i]);
    }
    #pragma unroll
    for (int i = 0; i < 16; ++i) {
        int gr = rowbase + rg * 16 + i;
        if (gr < NN) H[gr * 64 + c] = acc[i];
    }
}

// Y[n] = selfn[n]*H[n] + sum_{e in CSR(n)} norm_e * H[src_e]   (wave per node)
__global__ __launch_bounds__(256) void k_gather(const float* __restrict__ H,
                                                const float* __restrict__ selfn,
                                                const int* __restrict__ rowptr,
                                                const int2* __restrict__ epair,
                                                float* __restrict__ Y) {
    int node = blockIdx.x * 4 + (threadIdx.x >> 6);
    int lane = threadIdx.x & 63;
    int beg = rowptr[node], end = rowptr[node + 1];
    float acc = H[node * 64 + lane] * selfn[node];
    for (int e = beg; e < end; ++e) {
        int2 p = epair[e];
        acc = fmaf(H[p.x * 64 + lane], __int_as_float(p.y), acc);
    }
    Y[node * 64 + lane] = acc;
}

// out[n] = relu(relu(Y5[n]+b5) @ fW1 + fb1) @ fW2 + fb2
__global__ __launch_bounds__(256) void k_final(const float* __restrict__ Y5,
                                               const float* __restrict__ b5,
                                               const float* __restrict__ fW1,
                                               const float* __restrict__ fb1,
                                               const float* __restrict__ fW2,
                                               const float* __restrict__ fb2,
                                               float* __restrict__ out) {
    __shared__ float sW[64 * 64];
    __shared__ float sw2[64];
    int tid = threadIdx.x;
    #pragma unroll
    for (int i = 0; i < 16; ++i) sW[tid + i * 256] = fW1[tid + i * 256];
    if (tid < 64) sw2[tid] = fW2[tid];
    __syncthreads();
    int node = blockIdx.x * 4 + (tid >> 6);
    int lane = tid & 63;
    float v = fmaxf(Y5[node * 64 + lane] + b5[lane], 0.f);
    float u = fb1[lane];
    #pragma unroll
    for (int k = 0; k < 64; ++k) {
        float vk = __shfl(v, k, 64);
        u = fmaf(vk, sW[k * 64 + lane], u);
    }
    u = fmaxf(u, 0.f);
    float t = u * sw2[lane];
    #pragma unroll
    for (int off = 32; off > 0; off >>= 1) t += __shfl_down(t, off, 64);
    if (lane == 0) out[node] = t + fb2[0];
}

// ---------------- Launch ----------------

extern "C" void kernel_launch(void* const* d_in, const int* in_sizes, int n_in,
                              void* d_out, int out_size, void* d_ws, size_t ws_size,
                              hipStream_t stream) {
    const float* x   = (const float*)d_in[0];
    const int*   ei  = (const int*)d_in[1];
    const float* ew  = (const float*)d_in[2];
    const float* W1  = (const float*)d_in[3];
    const float* b1  = (const float*)d_in[4];
    const float* W2  = (const float*)d_in[5];
    const float* b2  = (const float*)d_in[6];
    const float* W3  = (const float*)d_in[7];
    const float* b3  = (const float*)d_in[8];
    const float* W4  = (const float*)d_in[9];
    const float* b4  = (const float*)d_in[10];
    const float* W5  = (const float*)d_in[11];
    const float* b5  = (const float*)d_in[12];
    const float* fW1 = (const float*)d_in[13];
    const float* fb1 = (const float*)d_in[14];
    const float* fW2 = (const float*)d_in[15];
    const float* fb2 = (const float*)d_in[16];
    float* out = (float*)d_out;

    char* ws = (char*)d_ws;
    size_t o = 0;
    auto alloc = [&](size_t elems) -> void* {
        void* p = (void*)(ws + o);
        o += ((elems * 4 + 255) / 256) * 256;
        return p;
    };
    float* dinv   = (float*)alloc(NN);       // deg, then dinv (in place)
    float* selfn  = (float*)alloc(NN);
    int*   rowptr = (int*)alloc(NN + 1);
    int*   cnt    = (int*)alloc(NN);         // count, then cursor (in place)
    int*   bsum   = (int*)alloc(128);
    int*   boff   = (int*)alloc(128);
    int2*  epair  = (int2*)alloc(2 * (size_t)EE);
    float* Hb     = (float*)alloc((size_t)NN * 64);
    float* bufA   = (float*)alloc((size_t)NN * 64);
    float* bufB   = (float*)alloc((size_t)NN * 64);

    int gN  = (NN + 255) / 256;
    int gE  = (EE + 255) / 256;
    int nb  = (NN + 1023) / 1024;    // 98
    int gNW = NN / 4;                // 25000 (wave-per-node kernels), N % 4 == 0
    int gG  = (NN + 63) / 64;        // 1563 gemm row-tiles

    k_zero<<<gN, 256, 0, stream>>>(dinv, cnt);
    k_count<<<gE, 256, 0, stream>>>(ei, ew, dinv, cnt);
    k_dinv<<<gN, 256, 0, stream>>>(dinv, selfn);
    k_bsum<<<nb, 256, 0, stream>>>(cnt, bsum);
    k_bscan<<<1, 64, 0, stream>>>(bsum, boff, nb);
    k_scan_out<<<nb, 256, 0, stream>>>(cnt, boff, rowptr);
    k_fill<<<gE, 256, 0, stream>>>(ei, ew, dinv, cnt, epair);

    // Layer 1
    k_layer1<<<NN * 64 / 256, 256, 0, stream>>>(x, W1, Hb);
    k_gather<<<gNW, 256, 0, stream>>>(Hb, selfn, rowptr, epair, bufA);

    // Layers 2..5
    const float* Ws[4] = {W2, W3, W4, W5};
    const float* bs[4] = {b1, b2, b3, b4};
    float* Xc = bufA; float* Yc = bufB;
    for (int l = 0; l < 4; ++l) {
        gemm_bias_relu<<<gG, 256, 0, stream>>>(Xc, bs[l], Ws[l], Hb);
        k_gather<<<gNW, 256, 0, stream>>>(Hb, selfn, rowptr, epair, Yc);
        float* t = Xc; Xc = Yc; Yc = t;
    }

    // Head: relu(Xc + b5) @ fW1 + fb1 -> relu -> @ fW2 + fb2
    k_final<<<gNW, 256, 0, stream>>>(Xc, b5, fW1, fb1, fW2, fb2, out);
}

// Round 2
// 659.304 us; speedup vs baseline: 1.6771x; 1.6771x over previous
//
#include <hip/hip_runtime.h>
#include <hip/hip_bf16.h>

#define NN 100000
#define EE 1250000

// ---------------- CSR build ----------------

__global__ __launch_bounds__(256) void k_zero(float* deg, int* count) {
    int i = blockIdx.x * 256 + threadIdx.x;
    if (i < NN) { deg[i] = 0.f; count[i] = 0; }
}

__global__ __launch_bounds__(256) void k_count(const int* __restrict__ ei,
                                               const float* __restrict__ ew,
                                               float* __restrict__ deg,
                                               int* __restrict__ count) {
    int e = blockIdx.x * 256 + threadIdx.x;
    if (e >= EE) return;
    int d = __builtin_nontemporal_load(&ei[EE + e]);
    float w = __builtin_nontemporal_load(&ew[e]);
    atomicAdd(&deg[d], w);
    atomicAdd(&count[d], 1);
}

__global__ __launch_bounds__(256) void k_dinv(float* __restrict__ deg_dinv,
                                              float* __restrict__ selfn) {
    int i = blockIdx.x * 256 + threadIdx.x;
    if (i >= NN) return;
    float d = deg_dinv[i] + 1.0f;   // self-loop weight 1.0 => deg always > 0
    float di = rsqrtf(d);
    deg_dinv[i] = di;
    selfn[i] = di * di;
}

__global__ __launch_bounds__(256) void k_bsum(const int* __restrict__ count, int* __restrict__ bsum) {
    __shared__ int ls[256];
    int b = blockIdx.x, tid = threadIdx.x;
    int base = b * 1024 + tid * 4;
    int s = 0;
    #pragma unroll
    for (int j = 0; j < 4; ++j) { int g = base + j; if (g < NN) s += count[g]; }
    ls[tid] = s; __syncthreads();
    for (int off = 128; off > 0; off >>= 1) {
        if (tid < off) ls[tid] += ls[tid + off];
        __syncthreads();
    }
    if (tid == 0) bsum[b] = ls[0];
}

// single-wave scan over nb<=128 block sums
__global__ void k_bscan(const int* __restrict__ bsum, int* __restrict__ boff, int nb) {
    int lane = threadIdx.x & 63;
    int v0 = (lane < nb) ? bsum[lane] : 0;
    int v1 = (64 + lane < nb) ? bsum[64 + lane] : 0;
    int s0 = v0, s1 = v1;
    #pragma unroll
    for (int d = 1; d < 64; d <<= 1) {
        int t0 = __shfl_up(s0, d, 64);
        int t1 = __shfl_up(s1, d, 64);
        if (lane >= d) { s0 += t0; s1 += t1; }
    }
    int tot0 = __shfl(s0, 63, 64);
    s1 += tot0;
    if (lane < nb) boff[lane] = s0 - v0;
    if (64 + lane < nb) boff[64 + lane] = s1 - v1;
}

// count[] is transformed in-place into cursor[] (exclusive prefix per element)
__global__ __launch_bounds__(256) void k_scan_out(int* __restrict__ count_cursor,
                                                  const int* __restrict__ boff,
                                                  int* __restrict__ rowptr) {
    __shared__ int ls[256];
    int b = blockIdx.x, tid = threadIdx.x;
    int base = b * 1024 + tid * 4;
    int c[4]; int s = 0;
    #pragma unroll
    for (int j = 0; j < 4; ++j) {
        int g = base + j;
        c[j] = (g < NN) ? count_cursor[g] : 0;
        s += c[j];
    }
    ls[tid] = s; __syncthreads();
    for (int off = 1; off < 256; off <<= 1) {
        int v = (tid >= off) ? ls[tid - off] : 0;
        __syncthreads();
        ls[tid] += v;
        __syncthreads();
    }
    int excl = ls[tid] - s + boff[b];
    #pragma unroll
    for (int j = 0; j < 4; ++j) {
        int g = base + j;
        if (g < NN) {
            count_cursor[g] = excl;       // cursor for fill
            rowptr[g + 1] = excl + c[j];  // inclusive => rowptr[g+1]
            excl += c[j];
        }
    }
    if (b == 0 && tid == 0) rowptr[0] = 0;
}

__global__ __launch_bounds__(256) void k_fill(const int* __restrict__ ei,
                                              const float* __restrict__ ew,
                                              const float* __restrict__ dinv,
                                              int* __restrict__ cursor,
                                              int2* __restrict__ epair) {
    int e = blockIdx.x * 256 + threadIdx.x;
    if (e >= EE) return;
    int s = __builtin_nontemporal_load(&ei[e]);
    int d = __builtin_nontemporal_load(&ei[EE + e]);
    float w = __builtin_nontemporal_load(&ew[e]);
    float nrm = dinv[s] * w * dinv[d];
    int p = atomicAdd(&cursor[d], 1);
    epair[p] = make_int2(s, __float_as_int(nrm));
}

// ---------------- Fused layers ----------------
// Layer l pipeline: G_l given (N x 64). Per node (one wave):
//   acc = selfn*G_l[node] + sum_e nrm_e * G_l[src_e]        (gather, 8 loads in flight)
//   v   = relu(acc + b_l)                                   (row across 64 lanes)
//   G_{l+1}[node] = v @ W_{l+1}                             (readlane-broadcast matvec, W in VGPRs)

#define RL(x, l) __builtin_amdgcn_readlane((x), (l))
#define RLF(x, l) __int_as_float(__builtin_amdgcn_readlane(__float_as_int(x), (l)))

// Layer 1 special case: G1 = x @ W1 is rank-1 -> aggregation is scalar.
__global__ __launch_bounds__(256, 4) void k_fused1(
    const float* __restrict__ x, const float* __restrict__ selfn,
    const int* __restrict__ rowptr, const long long* __restrict__ epair,
    const float* __restrict__ W1, const float* __restrict__ b1,
    const float* __restrict__ W2, float* __restrict__ Gout)
{
    int lane = threadIdx.x & 63;
    int wid  = threadIdx.x >> 6;
    float w[64];
    #pragma unroll
    for (int k = 0; k < 64; ++k) w[k] = W2[k * 64 + lane];
    float w1l = W1[lane], b1l = b1[lane];
    int stride = gridDim.x * 4;
    for (int node = blockIdx.x * 4 + wid; node < NN; node += stride) {
        int beg = rowptr[node], end = rowptr[node + 1];
        float partial = 0.f;
        for (int base = beg; base < end; base += 64) {
            int idx = base + lane;
            if (idx < end) {
                long long pl = __builtin_nontemporal_load(&epair[idx]);
                int s = (int)(pl & 0xffffffffLL);
                float nrm = __int_as_float((int)(pl >> 32));
                partial = fmaf(x[s], nrm, partial);
            }
        }
        #pragma unroll
        for (int m = 32; m >= 1; m >>= 1) partial += __shfl_xor(partial, m, 64);
        float sagg = partial + selfn[node] * x[node];
        float v = fmaxf(fmaf(sagg, w1l, b1l), 0.f);
        float u0 = 0.f, u1 = 0.f, u2 = 0.f, u3 = 0.f;
        #pragma unroll
        for (int k = 0; k < 64; k += 4) {
            u0 = fmaf(RLF(v, k),     w[k],     u0);
            u1 = fmaf(RLF(v, k + 1), w[k + 1], u1);
            u2 = fmaf(RLF(v, k + 2), w[k + 2], u2);
            u3 = fmaf(RLF(v, k + 3), w[k + 3], u3);
        }
        Gout[node * 64 + lane] = (u0 + u1) + (u2 + u3);
    }
}

__global__ __launch_bounds__(256, 4) void k_fused(
    const float* __restrict__ Gin, const float* __restrict__ selfn,
    const int* __restrict__ rowptr, const long long* __restrict__ epair,
    const float* __restrict__ bias, const float* __restrict__ Wnext,
    float* __restrict__ Gout)
{
    int lane = threadIdx.x & 63;
    int wid  = threadIdx.x >> 6;
    float w[64];
    #pragma unroll
    for (int k = 0; k < 64; ++k) w[k] = Wnext[k * 64 + lane];
    float blane = bias[lane];
    int stride = gridDim.x * 4;
    for (int node = blockIdx.x * 4 + wid; node < NN; node += stride) {
        int beg = rowptr[node], end = rowptr[node + 1];
        float acc = Gin[node * 64 + lane] * selfn[node];
        for (int base = beg; base < end; base += 64) {
            int idx = base + lane;
            long long pl = 0;
            if (idx < end) pl = __builtin_nontemporal_load(&epair[idx]);
            int px = (int)(pl & 0xffffffffLL);
            int py = (int)(pl >> 32);
            int cnt = min(64, end - base);
            int j = 0;
            for (; j + 8 <= cnt; j += 8) {       // 8 row-loads in flight
                float h[8], nv[8];
                #pragma unroll
                for (int t = 0; t < 8; ++t) {
                    int s = RL(px, j + t);
                    nv[t] = __int_as_float(RL(py, j + t));
                    h[t] = Gin[s * 64 + lane];
                }
                #pragma unroll
                for (int t = 0; t < 8; ++t) acc = fmaf(h[t], nv[t], acc);
            }
            for (; j + 4 <= cnt; j += 4) {
                float h[4], nv[4];
                #pragma unroll
                for (int t = 0; t < 4; ++t) {
                    int s = RL(px, j + t);
                    nv[t] = __int_as_float(RL(py, j + t));
                    h[t] = Gin[s * 64 + lane];
                }
                #pragma unroll
                for (int t = 0; t < 4; ++t) acc = fmaf(h[t], nv[t], acc);
            }
            for (; j < cnt; ++j) {
                int s = RL(px, j);
                float nv0 = __int_as_float(RL(py, j));
                acc = fmaf(Gin[s * 64 + lane], nv0, acc);
            }
        }
        float v = fmaxf(acc + blane, 0.f);
        float u0 = 0.f, u1 = 0.f, u2 = 0.f, u3 = 0.f;
        #pragma unroll
        for (int k = 0; k < 64; k += 4) {
            u0 = fmaf(RLF(v, k),     w[k],     u0);
            u1 = fmaf(RLF(v, k + 1), w[k + 1], u1);
            u2 = fmaf(RLF(v, k + 2), w[k + 2], u2);
            u3 = fmaf(RLF(v, k + 3), w[k + 3], u3);
        }
        Gout[node * 64 + lane] = (u0 + u1) + (u2 + u3);
    }
}

// Last gather + MLP head: out = relu(relu(Agg(G5)+b5) @ fW1 + fb1) @ fW2 + fb2
__global__ __launch_bounds__(256, 4) void k_head(
    const float* __restrict__ Gin, const float* __restrict__ selfn,
    const int* __restrict__ rowptr, const long long* __restrict__ epair,
    const float* __restrict__ b5, const float* __restrict__ fW1,
    const float* __restrict__ fb1, const float* __restrict__ fW2,
    const float* __restrict__ fb2, float* __restrict__ out)
{
    int lane = threadIdx.x & 63;
    int wid  = threadIdx.x >> 6;
    float w[64];
    #pragma unroll
    for (int k = 0; k < 64; ++k) w[k] = fW1[k * 64 + lane];
    float b5l = b5[lane], fb1l = fb1[lane], fw2l = fW2[lane], fb2s = fb2[0];
    int stride = gridDim.x * 4;
    for (int node = blockIdx.x * 4 + wid; node < NN; node += stride) {
        int beg = rowptr[node], end = rowptr[node + 1];
        float acc = Gin[node * 64 + lane] * selfn[node];
        for (int base = beg; base < end; base += 64) {
            int idx = base + lane;
            long long pl = 0;
            if (idx < end) pl = __builtin_nontemporal_load(&epair[idx]);
            int px = (int)(pl & 0xffffffffLL);
            int py = (int)(pl >> 32);
            int cnt = min(64, end - base);
            int j = 0;
            for (; j + 8 <= cnt; j += 8) {
                float h[8], nv[8];
                #pragma unroll
                for (int t = 0; t < 8; ++t) {
                    int s = RL(px, j + t);
                    nv[t] = __int_as_float(RL(py, j + t));
                    h[t] = Gin[s * 64 + lane];
                }
                #pragma unroll
                for (int t = 0; t < 8; ++t) acc = fmaf(h[t], nv[t], acc);
            }
            for (; j + 4 <= cnt; j += 4) {
                float h[4], nv[4];
                #pragma unroll
                for (int t = 0; t < 4; ++t) {
                    int s = RL(px, j + t);
                    nv[t] = __int_as_float(RL(py, j + t));
                    h[t] = Gin[s * 64 + lane];
                }
                #pragma unroll
                for (int t = 0; t < 4; ++t) acc = fmaf(h[t], nv[t], acc);
            }
            for (; j < cnt; ++j) {
                int s = RL(px, j);
                float nv0 = __int_as_float(RL(py, j));
                acc = fmaf(Gin[s * 64 + lane], nv0, acc);
            }
        }
        float v = fmaxf(acc + b5l, 0.f);
        float u0 = 0.f, u1 = 0.f, u2 = 0.f, u3 = 0.f;
        #pragma unroll
        for (int k = 0; k < 64; k += 4) {
            u0 = fmaf(RLF(v, k),     w[k],     u0);
            u1 = fmaf(RLF(v, k + 1), w[k + 1], u1);
            u2 = fmaf(RLF(v, k + 2), w[k + 2], u2);
            u3 = fmaf(RLF(v, k + 3), w[k + 3], u3);
        }
        float u = fmaxf((u0 + u1) + (u2 + u3) + fb1l, 0.f);
        float t = u * fw2l;
        #pragma unroll
        for (int m = 32; m >= 1; m >>= 1) t += __shfl_xor(t, m, 64);
        if (lane == 0) out[node] = t + fb2s;
    }
}

// ---------------- Launch ----------------

extern "C" void kernel_launch(void* const* d_in, const int* in_sizes, int n_in,
                              void* d_out, int out_size, void* d_ws, size_t ws_size,
                              hipStream_t stream) {
    const float* x   = (const float*)d_in[0];
    const int*   ei  = (const int*)d_in[1];
    const float* ew  = (const float*)d_in[2];
    const float* W1  = (const float*)d_in[3];
    const float* b1  = (const float*)d_in[4];
    const float* W2  = (const float*)d_in[5];
    const float* b2  = (const float*)d_in[6];
    const float* W3  = (const float*)d_in[7];
    const float* b3  = (const float*)d_in[8];
    const float* W4  = (const float*)d_in[9];
    const float* b4  = (const float*)d_in[10];
    const float* b5  = (const float*)d_in[12];
    const float* W5  = (const float*)d_in[11];
    const float* fW1 = (const float*)d_in[13];
    const float* fb1 = (const float*)d_in[14];
    const float* fW2 = (const float*)d_in[15];
    const float* fb2 = (const float*)d_in[16];
    float* out = (float*)d_out;

    char* ws = (char*)d_ws;
    size_t o = 0;
    auto alloc = [&](size_t elems) -> void* {
        void* p = (void*)(ws + o);
        o += ((elems * 4 + 255) / 256) * 256;
        return p;
    };
    float* dinv   = (float*)alloc(NN);       // deg, then dinv (in place)
    float* selfn  = (float*)alloc(NN);
    int*   rowptr = (int*)alloc(NN + 1);
    int*   cnt    = (int*)alloc(NN);         // count, then cursor (in place)
    int*   bsum   = (int*)alloc(128);
    int*   boff   = (int*)alloc(128);
    int2*  epair  = (int2*)alloc(2 * (size_t)EE);
    float* Ga     = (float*)alloc((size_t)NN * 64);
    float* Gb     = (float*)alloc((size_t)NN * 64);
    const long long* epll = (const long long*)epair;

    int gN  = (NN + 255) / 256;
    int gE  = (EE + 255) / 256;
    int nb  = (NN + 1023) / 1024;    // 98
    int gF  = 1024;                  // fused kernels: grid-stride, 4 blocks/CU @ 16 waves/CU

    k_zero<<<gN, 256, 0, stream>>>(dinv, cnt);
    k_count<<<gE, 256, 0, stream>>>(ei, ew, dinv, cnt);
    k_dinv<<<gN, 256, 0, stream>>>(dinv, selfn);
    k_bsum<<<nb, 256, 0, stream>>>(cnt, bsum);
    k_bscan<<<1, 64, 0, stream>>>(bsum, boff, nb);
    k_scan_out<<<nb, 256, 0, stream>>>(cnt, boff, rowptr);
    k_fill<<<gE, 256, 0, stream>>>(ei, ew, dinv, cnt, epair);

    // G2 = relu(Agg(x@W1)+b1) @ W2
    k_fused1<<<gF, 256, 0, stream>>>(x, selfn, rowptr, epll, W1, b1, W2, Ga);
    // G3 = relu(Agg(G2)+b2) @ W3
    k_fused<<<gF, 256, 0, stream>>>(Ga, selfn, rowptr, epll, b2, W3, Gb);
    // G4 = relu(Agg(G3)+b3) @ W4
    k_fused<<<gF, 256, 0, stream>>>(Gb, selfn, rowptr, epll, b3, W4, Ga);
    // G5 = relu(Agg(G4)+b4) @ W5
    k_fused<<<gF, 256, 0, stream>>>(Ga, selfn, rowptr, epll, b4, W5, Gb);
    // out = head(Agg(G5))
    k_head<<<gF, 256, 0, stream>>>(Gb, selfn, rowptr, epll, b5, fW1, fb1, fW2, fb2, out);
}

// Round 3
// 600.341 us; speedup vs baseline: 1.8418x; 1.0982x over previous
//
#include <hip/hip_runtime.h>
#include <hip/hip_bf16.h>

#define NN 100000
#define EE 1250000

#define RL(x, l) __builtin_amdgcn_readlane((x), (l))
#define RLF(x, l) __int_as_float(__builtin_amdgcn_readlane(__float_as_int(x), (l)))

// ---------------- CSR build ----------------

__global__ __launch_bounds__(256) void k_zero(int* cnt) {
    int i = blockIdx.x * 256 + threadIdx.x;
    if (i < NN) cnt[i] = 0;
}

// one atomic per edge: slot within dst row
__global__ __launch_bounds__(256) void k_count(const int* __restrict__ ei,
                                               int* __restrict__ cnt,
                                               int* __restrict__ slot) {
    int e = blockIdx.x * 256 + threadIdx.x;
    if (e >= EE) return;
    int d = __builtin_nontemporal_load(&ei[EE + e]);
    slot[e] = atomicAdd(&cnt[d], 1);
}

__global__ __launch_bounds__(256) void k_bsum(const int* __restrict__ cnt, int* __restrict__ bsum) {
    __shared__ int ls[256];
    int b = blockIdx.x, tid = threadIdx.x;
    int base = b * 1024 + tid * 4;
    int s = 0;
    #pragma unroll
    for (int j = 0; j < 4; ++j) { int g = base + j; if (g < NN) s += cnt[g]; }
    ls[tid] = s; __syncthreads();
    for (int off = 128; off > 0; off >>= 1) {
        if (tid < off) ls[tid] += ls[tid + off];
        __syncthreads();
    }
    if (tid == 0) bsum[b] = ls[0];
}

// single-wave scan over nb<=128 block sums
__global__ void k_bscan(const int* __restrict__ bsum, int* __restrict__ boff, int nb) {
    int lane = threadIdx.x & 63;
    int v0 = (lane < nb) ? bsum[lane] : 0;
    int v1 = (64 + lane < nb) ? bsum[64 + lane] : 0;
    int s0 = v0, s1 = v1;
    #pragma unroll
    for (int d = 1; d < 64; d <<= 1) {
        int t0 = __shfl_up(s0, d, 64);
        int t1 = __shfl_up(s1, d, 64);
        if (lane >= d) { s0 += t0; s1 += t1; }
    }
    int tot0 = __shfl(s0, 63, 64);
    s1 += tot0;
    if (lane < nb) boff[lane] = s0 - v0;
    if (64 + lane < nb) boff[64 + lane] = s1 - v1;
}

__global__ __launch_bounds__(256) void k_scan_out(const int* __restrict__ cnt,
                                                  const int* __restrict__ boff,
                                                  int* __restrict__ rowptr) {
    __shared__ int ls[256];
    int b = blockIdx.x, tid = threadIdx.x;
    int base = b * 1024 + tid * 4;
    int c[4]; int s = 0;
    #pragma unroll
    for (int j = 0; j < 4; ++j) {
        int g = base + j;
        c[j] = (g < NN) ? cnt[g] : 0;
        s += c[j];
    }
    ls[tid] = s; __syncthreads();
    for (int off = 1; off < 256; off <<= 1) {
        int v = (tid >= off) ? ls[tid - off] : 0;
        __syncthreads();
        ls[tid] += v;
        __syncthreads();
    }
    int excl = ls[tid] - s + boff[b];
    #pragma unroll
    for (int j = 0; j < 4; ++j) {
        int g = base + j;
        if (g < NN) {
            rowptr[g + 1] = excl + c[j];
            excl += c[j];
        }
    }
    if (b == 0 && tid == 0) rowptr[0] = 0;
}

// atomic-free fill: epair[p] = (src, raw edge weight)
__global__ __launch_bounds__(256) void k_fill(const int* __restrict__ ei,
                                              const float* __restrict__ ew,
                                              const int* __restrict__ slot,
                                              const int* __restrict__ rowptr,
                                              int2* __restrict__ epair) {
    int e = blockIdx.x * 256 + threadIdx.x;
    if (e >= EE) return;
    int s = __builtin_nontemporal_load(&ei[e]);
    int d = __builtin_nontemporal_load(&ei[EE + e]);
    float w = __builtin_nontemporal_load(&ew[e]);
    int sl = __builtin_nontemporal_load(&slot[e]);
    int p = rowptr[d] + sl;
    epair[p] = make_int2(s, __float_as_int(w));
}

// deg[n] = 1 + sum_row ew -> dinv, selfn.  4 nodes per wave (16 lanes each).
__global__ __launch_bounds__(256) void k_deg(const int* __restrict__ rowptr,
                                             const int2* __restrict__ epair,
                                             float* __restrict__ dinv,
                                             float* __restrict__ selfn) {
    int lane = threadIdx.x & 63;
    int wid  = threadIdx.x >> 6;
    int l16  = lane & 15;
    int sub  = lane >> 4;
    int node = (blockIdx.x * 4 + wid) * 4 + sub;
    if (node >= NN) return;
    int beg = rowptr[node], end = rowptr[node + 1];
    float s = 0.f;
    for (int idx = beg + l16; idx < end; idx += 16)
        s += __int_as_float(epair[idx].y);
    #pragma unroll
    for (int m = 8; m >= 1; m >>= 1) s += __shfl_xor(s, m, 64);
    if (l16 == 0) {
        float di = rsqrtf(s + 1.0f);
        dinv[node] = di;
        selfn[node] = di * di;
    }
}

// epair.y <- dinv[src]*ew*dinv[dst]
__global__ __launch_bounds__(256) void k_scale(const int* __restrict__ rowptr,
                                               const float* __restrict__ dinv,
                                               int2* __restrict__ epair) {
    int lane = threadIdx.x & 63;
    int wid  = threadIdx.x >> 6;
    int l16  = lane & 15;
    int sub  = lane >> 4;
    int node = (blockIdx.x * 4 + wid) * 4 + sub;
    if (node >= NN) return;
    int beg = rowptr[node], end = rowptr[node + 1];
    float din = dinv[node];
    for (int idx = beg + l16; idx < end; idx += 16) {
        int2 p = epair[idx];
        float nrm = dinv[p.x] * __int_as_float(p.y) * din;
        epair[idx] = make_int2(p.x, __float_as_int(nrm));
    }
}

// ---------------- Layers ----------------

// Layer 1 fused: G2 = relu(Agg(x@W1)+b1) @ W2  (aggregation of scalar x)
__global__ __launch_bounds__(256, 4) void k_fused1(
    const float* __restrict__ x, const float* __restrict__ selfn,
    const int* __restrict__ rowptr, const long long* __restrict__ epair,
    const float* __restrict__ W1, const float* __restrict__ b1,
    const float* __restrict__ W2, float* __restrict__ Gout)
{
    int lane = threadIdx.x & 63;
    int wid  = threadIdx.x >> 6;
    float w[64];
    #pragma unroll
    for (int k = 0; k < 64; ++k) w[k] = W2[k * 64 + lane];
    float w1l = W1[lane], b1l = b1[lane];
    int stride = gridDim.x * 4;
    for (int node = blockIdx.x * 4 + wid; node < NN; node += stride) {
        int beg = rowptr[node], end = rowptr[node + 1];
        float partial = 0.f;
        for (int base = beg; base < end; base += 64) {
            int idx = base + lane;
            if (idx < end) {
                long long pl = __builtin_nontemporal_load(&epair[idx]);
                int s = (int)(pl & 0xffffffffLL);
                float nrm = __int_as_float((int)(pl >> 32));
                partial = fmaf(x[s], nrm, partial);
            }
        }
        #pragma unroll
        for (int m = 32; m >= 1; m >>= 1) partial += __shfl_xor(partial, m, 64);
        float sagg = partial + selfn[node] * x[node];
        float v = fmaxf(fmaf(sagg, w1l, b1l), 0.f);
        float u0 = 0.f, u1 = 0.f;
        #pragma unroll
        for (int k = 0; k < 64; k += 2) {
            u0 = fmaf(RLF(v, k),     w[k],     u0);
            u1 = fmaf(RLF(v, k + 1), w[k + 1], u1);
        }
        Gout[node * 64 + lane] = u0 + u1;
    }
}

// Pure aggregation: Y[n] = selfn[n]*G[n] + sum_e nrm_e * G[src_e]
// Wave per node; 16 row loads in flight; epair via wave-uniform indices.
__global__ __launch_bounds__(256, 4) void k_gather(
    const float* __restrict__ G, const float* __restrict__ selfn,
    const int* __restrict__ rowptr, const int2* __restrict__ ep,
    float* __restrict__ Y)
{
    int lane = threadIdx.x & 63;
    int wid  = threadIdx.x >> 6;
    int stride = gridDim.x * 4;
    for (int node = blockIdx.x * 4 + wid; node < NN; node += stride) {
        int beg = __builtin_amdgcn_readfirstlane(rowptr[node]);
        int end = __builtin_amdgcn_readfirstlane(rowptr[node + 1]);
        float acc0 = G[node * 64 + lane] * selfn[node];
        float acc1 = 0.f;
        int j = beg;
        for (; j + 16 <= end; j += 16) {
            float h[16], nv[16];
            #pragma unroll
            for (int t = 0; t < 16; ++t) {
                int2 p = ep[j + t];          // uniform address -> scalar load
                h[t]  = G[p.x * 64 + lane];
                nv[t] = __int_as_float(p.y);
            }
            #pragma unroll
            for (int t = 0; t < 16; t += 2) {
                acc0 = fmaf(h[t],     nv[t],     acc0);
                acc1 = fmaf(h[t + 1], nv[t + 1], acc1);
            }
        }
        if (j < end) {                        // masked tail, still batched
            float h[16], nv[16];
            #pragma unroll
            for (int t = 0; t < 16; ++t) {
                int idx = j + t;
                bool valid = idx < end;       // wave-uniform predicate
                int2 p = ep[valid ? idx : j];
                h[t]  = G[p.x * 64 + lane];
                nv[t] = valid ? __int_as_float(p.y) : 0.f;
            }
            #pragma unroll
            for (int t = 0; t < 16; t += 2) {
                acc0 = fmaf(h[t],     nv[t],     acc0);
                acc1 = fmaf(h[t + 1], nv[t + 1], acc1);
            }
        }
        Y[node * 64 + lane] = acc0 + acc1;
    }
}

// H = relu(Y + bias) @ W   — 4 nodes per wave, W held in VGPRs
__global__ __launch_bounds__(256, 4) void k_mv(
    const float* __restrict__ Y, const float* __restrict__ bias,
    const float* __restrict__ W, float* __restrict__ H)
{
    int lane = threadIdx.x & 63;
    int wid  = threadIdx.x >> 6;
    float w[64];
    #pragma unroll
    for (int k = 0; k < 64; ++k) w[k] = W[k * 64 + lane];
    float bl = bias[lane];
    const int ngrp = NN / 4;                 // 25000
    int stride = gridDim.x * 4;
    for (int grp = blockIdx.x * 4 + wid; grp < ngrp; grp += stride) {
        int n0 = grp * 4;
        float v0 = fmaxf(Y[(n0 + 0) * 64 + lane] + bl, 0.f);
        float v1 = fmaxf(Y[(n0 + 1) * 64 + lane] + bl, 0.f);
        float v2 = fmaxf(Y[(n0 + 2) * 64 + lane] + bl, 0.f);
        float v3 = fmaxf(Y[(n0 + 3) * 64 + lane] + bl, 0.f);
        float a0 = 0.f, a1 = 0.f, a2 = 0.f, a3 = 0.f;
        #pragma unroll
        for (int k = 0; k < 64; ++k) {
            float wk = w[k];
            a0 = fmaf(RLF(v0, k), wk, a0);
            a1 = fmaf(RLF(v1, k), wk, a1);
            a2 = fmaf(RLF(v2, k), wk, a2);
            a3 = fmaf(RLF(v3, k), wk, a3);
        }
        H[(n0 + 0) * 64 + lane] = a0;
        H[(n0 + 1) * 64 + lane] = a1;
        H[(n0 + 2) * 64 + lane] = a2;
        H[(n0 + 3) * 64 + lane] = a3;
    }
}

// out = relu(relu(Y+b5)@fW1 + fb1) @ fW2 + fb2   — 4 nodes per wave
__global__ __launch_bounds__(256, 4) void k_head(
    const float* __restrict__ Y, const float* __restrict__ b5,
    const float* __restrict__ fW1, const float* __restrict__ fb1,
    const float* __restrict__ fW2, const float* __restrict__ fb2,
    float* __restrict__ out)
{
    int lane = threadIdx.x & 63;
    int wid  = threadIdx.x >> 6;
    float w[64];
    #pragma unroll
    for (int k = 0; k < 64; ++k) w[k] = fW1[k * 64 + lane];
    float bl = b5[lane], fb1l = fb1[lane], fw2l = fW2[lane], fb2s = fb2[0];
    const int ngrp = NN / 4;
    int stride = gridDim.x * 4;
    for (int grp = blockIdx.x * 4 + wid; grp < ngrp; grp += stride) {
        int n0 = grp * 4;
        float v0 = fmaxf(Y[(n0 + 0) * 64 + lane] + bl, 0.f);
        float v1 = fmaxf(Y[(n0 + 1) * 64 + lane] + bl, 0.f);
        float v2 = fmaxf(Y[(n0 + 2) * 64 + lane] + bl, 0.f);
        float v3 = fmaxf(Y[(n0 + 3) * 64 + lane] + bl, 0.f);
        float a0 = 0.f, a1 = 0.f, a2 = 0.f, a3 = 0.f;
        #pragma unroll
        for (int k = 0; k < 64; ++k) {
            float wk = w[k];
            a0 = fmaf(RLF(v0, k), wk, a0);
            a1 = fmaf(RLF(v1, k), wk, a1);
            a2 = fmaf(RLF(v2, k), wk, a2);
            a3 = fmaf(RLF(v3, k), wk, a3);
        }
        float t0 = fmaxf(a0 + fb1l, 0.f) * fw2l;
        float t1 = fmaxf(a1 + fb1l, 0.f) * fw2l;
        float t2 = fmaxf(a2 + fb1l, 0.f) * fw2l;
        float t3 = fmaxf(a3 + fb1l, 0.f) * fw2l;
        #pragma unroll
        for (int m = 32; m >= 1; m >>= 1) {
            t0 += __shfl_xor(t0, m, 64);
            t1 += __shfl_xor(t1, m, 64);
            t2 += __shfl_xor(t2, m, 64);
            t3 += __shfl_xor(t3, m, 64);
        }
        if (lane == 0) {
            out[n0 + 0] = t0 + fb2s;
            out[n0 + 1] = t1 + fb2s;
            out[n0 + 2] = t2 + fb2s;
            out[n0 + 3] = t3 + fb2s;
        }
    }
}

// ---------------- Launch ----------------

extern "C" void kernel_launch(void* const* d_in, const int* in_sizes, int n_in,
                              void* d_out, int out_size, void* d_ws, size_t ws_size,
                              hipStream_t stream) {
    const float* x   = (const float*)d_in[0];
    const int*   ei  = (const int*)d_in[1];
    const float* ew  = (const float*)d_in[2];
    const float* W1  = (const float*)d_in[3];
    const float* b1  = (const float*)d_in[4];
    const float* W2  = (const float*)d_in[5];
    const float* b2  = (const float*)d_in[6];
    const float* W3  = (const float*)d_in[7];
    const float* b3  = (const float*)d_in[8];
    const float* W4  = (const float*)d_in[9];
    const float* b4  = (const float*)d_in[10];
    const float* W5  = (const float*)d_in[11];
    const float* b5  = (const float*)d_in[12];
    const float* fW1 = (const float*)d_in[13];
    const float* fb1 = (const float*)d_in[14];
    const float* fW2 = (const float*)d_in[15];
    const float* fb2 = (const float*)d_in[16];
    float* out = (float*)d_out;

    char* ws = (char*)d_ws;
    size_t o = 0;
    auto alloc = [&](size_t elems) -> void* {
        void* p = (void*)(ws + o);
        o += ((elems * 4 + 255) / 256) * 256;
        return p;
    };
    float* dinv   = (float*)alloc(NN);
    float* selfn  = (float*)alloc(NN);
    int*   rowptr = (int*)alloc(NN + 1);
    int*   cnt    = (int*)alloc(NN);
    int*   bsum   = (int*)alloc(128);
    int*   boff   = (int*)alloc(128);
    int2*  epair  = (int2*)alloc(2 * (size_t)EE);
    float* Yb     = (float*)alloc((size_t)NN * 64);
    float* Ga     = (float*)alloc((size_t)NN * 64);
    float* Gb     = (float*)alloc((size_t)NN * 64);
    int*   slot   = (int*)Yb;   // aliased: slot dead before Yb first written
    const long long* epll = (const long long*)epair;

    int gN  = (NN + 255) / 256;
    int gE  = (EE + 255) / 256;
    int nb  = (NN + 1023) / 1024;    // 98
    int gW4 = NN / 16;               // 6250: 4 nodes/wave kernels
    int gF  = 1024;                  // grid-stride layer kernels

    k_zero<<<gN, 256, 0, stream>>>(cnt);
    k_count<<<gE, 256, 0, stream>>>(ei, cnt, slot);
    k_bsum<<<nb, 256, 0, stream>>>(cnt, bsum);
    k_bscan<<<1, 64, 0, stream>>>(bsum, boff, nb);
    k_scan_out<<<nb, 256, 0, stream>>>(cnt, boff, rowptr);
    k_fill<<<gE, 256, 0, stream>>>(ei, ew, slot, rowptr, epair);
    k_deg<<<gW4, 256, 0, stream>>>(rowptr, epair, dinv, selfn);
    k_scale<<<gW4, 256, 0, stream>>>(rowptr, dinv, epair);

    // G2 = relu(Agg(x@W1)+b1) @ W2
    k_fused1<<<gF, 256, 0, stream>>>(x, selfn, rowptr, epll, W1, b1, W2, Ga);
    // G3 = relu(Agg(G2)+b2) @ W3
    k_gather<<<gF, 256, 0, stream>>>(Ga, selfn, rowptr, epair, Yb);
    k_mv<<<gF, 256, 0, stream>>>(Yb, b2, W3, Gb);
    // G4
    k_gather<<<gF, 256, 0, stream>>>(Gb, selfn, rowptr, epair, Yb);
    k_mv<<<gF, 256, 0, stream>>>(Yb, b3, W4, Ga);
    // G5
    k_gather<<<gF, 256, 0, stream>>>(Ga, selfn, rowptr, epair, Yb);
    k_mv<<<gF, 256, 0, stream>>>(Yb, b4, W5, Gb);
    // head
    k_gather<<<gF, 256, 0, stream>>>(Gb, selfn, rowptr, epair, Yb);
    k_head<<<gF, 256, 0, stream>>>(Yb, b5, fW1, fb1, fW2, fb2, out);
}

// Round 4
// 560.468 us; speedup vs baseline: 1.9729x; 1.0711x over previous
//
#include <hip/hip_runtime.h>
#include <hip/hip_bf16.h>

#define NN 100000
#define EE 1250000

#define RL(x, l) __builtin_amdgcn_readlane((x), (l))
#define RLF(x, l) __int_as_float(__builtin_amdgcn_readlane(__float_as_int(x), (l)))

// ---------------- CSR build ----------------

__global__ __launch_bounds__(256) void k_zero(int* cnt) {
    int i = blockIdx.x * 256 + threadIdx.x;
    if (i < NN) cnt[i] = 0;
}

// one atomic per edge: slot within dst row
__global__ __launch_bounds__(256) void k_count(const int* __restrict__ ei,
                                               int* __restrict__ cnt,
                                               int* __restrict__ slot) {
    int e = blockIdx.x * 256 + threadIdx.x;
    if (e >= EE) return;
    int d = __builtin_nontemporal_load(&ei[EE + e]);
    slot[e] = atomicAdd(&cnt[d], 1);
}

__global__ __launch_bounds__(256) void k_bsum(const int* __restrict__ cnt, int* __restrict__ bsum) {
    __shared__ int ls[256];
    int b = blockIdx.x, tid = threadIdx.x;
    int base = b * 1024 + tid * 4;
    int s = 0;
    #pragma unroll
    for (int j = 0; j < 4; ++j) { int g = base + j; if (g < NN) s += cnt[g]; }
    ls[tid] = s; __syncthreads();
    for (int off = 128; off > 0; off >>= 1) {
        if (tid < off) ls[tid] += ls[tid + off];
        __syncthreads();
    }
    if (tid == 0) bsum[b] = ls[0];
}

// single-wave scan over nb<=128 block sums
__global__ void k_bscan(const int* __restrict__ bsum, int* __restrict__ boff, int nb) {
    int lane = threadIdx.x & 63;
    int v0 = (lane < nb) ? bsum[lane] : 0;
    int v1 = (64 + lane < nb) ? bsum[64 + lane] : 0;
    int s0 = v0, s1 = v1;
    #pragma unroll
    for (int d = 1; d < 64; d <<= 1) {
        int t0 = __shfl_up(s0, d, 64);
        int t1 = __shfl_up(s1, d, 64);
        if (lane >= d) { s0 += t0; s1 += t1; }
    }
    int tot0 = __shfl(s0, 63, 64);
    s1 += tot0;
    if (lane < nb) boff[lane] = s0 - v0;
    if (64 + lane < nb) boff[64 + lane] = s1 - v1;
}

__global__ __launch_bounds__(256) void k_scan_out(const int* __restrict__ cnt,
                                                  const int* __restrict__ boff,
                                                  int* __restrict__ rowptr) {
    __shared__ int ls[256];
    int b = blockIdx.x, tid = threadIdx.x;
    int base = b * 1024 + tid * 4;
    int c[4]; int s = 0;
    #pragma unroll
    for (int j = 0; j < 4; ++j) {
        int g = base + j;
        c[j] = (g < NN) ? cnt[g] : 0;
        s += c[j];
    }
    ls[tid] = s; __syncthreads();
    for (int off = 1; off < 256; off <<= 1) {
        int v = (tid >= off) ? ls[tid - off] : 0;
        __syncthreads();
        ls[tid] += v;
        __syncthreads();
    }
    int excl = ls[tid] - s + boff[b];
    #pragma unroll
    for (int j = 0; j < 4; ++j) {
        int g = base + j;
        if (g < NN) {
            rowptr[g + 1] = excl + c[j];
            excl += c[j];
        }
    }
    if (b == 0 && tid == 0) rowptr[0] = 0;
}

// atomic-free fill: epair[p] = (src, raw edge weight)
__global__ __launch_bounds__(256) void k_fill(const int* __restrict__ ei,
                                              const float* __restrict__ ew,
                                              const int* __restrict__ slot,
                                              const int* __restrict__ rowptr,
                                              int2* __restrict__ epair) {
    int e = blockIdx.x * 256 + threadIdx.x;
    if (e >= EE) return;
    int s = __builtin_nontemporal_load(&ei[e]);
    int d = __builtin_nontemporal_load(&ei[EE + e]);
    float w = __builtin_nontemporal_load(&ew[e]);
    int sl = __builtin_nontemporal_load(&slot[e]);
    int p = rowptr[d] + sl;
    epair[p] = make_int2(s, __float_as_int(w));
}

// deg[n] = 1 + sum_row ew -> dinv, selfn.  4 nodes per wave (16 lanes each).
__global__ __launch_bounds__(256) void k_deg(const int* __restrict__ rowptr,
                                             const int2* __restrict__ epair,
                                             float* __restrict__ dinv,
                                             float* __restrict__ selfn) {
    int lane = threadIdx.x & 63;
    int wid  = threadIdx.x >> 6;
    int l16  = lane & 15;
    int sub  = lane >> 4;
    int node = (blockIdx.x * 4 + wid) * 4 + sub;
    if (node >= NN) return;
    int beg = rowptr[node], end = rowptr[node + 1];
    float s = 0.f;
    for (int idx = beg + l16; idx < end; idx += 16)
        s += __int_as_float(epair[idx].y);
    #pragma unroll
    for (int m = 8; m >= 1; m >>= 1) s += __shfl_xor(s, m, 64);
    if (l16 == 0) {
        float di = rsqrtf(s + 1.0f);
        dinv[node] = di;
        selfn[node] = di * di;
    }
}

// ---------------- Layers ----------------

// Layer 1 fused + inline edge scaling:
//   nrm = dinv[s]*w*dinv[d]; epair <- (s, nrm)   [persisted for layers 2..5]
//   G2 = relu(Agg(x@W1)+b1) @ W2
__global__ __launch_bounds__(256, 4) void k_fused1(
    const float* __restrict__ x, const float* __restrict__ dinv,
    const float* __restrict__ selfn,
    const int* __restrict__ rowptr, int2* __restrict__ ep,
    const float* __restrict__ W1, const float* __restrict__ b1,
    const float* __restrict__ W2, float* __restrict__ Gout)
{
    int lane = threadIdx.x & 63;
    int node = blockIdx.x * 4 + (threadIdx.x >> 6);   // grid = NN/4
    float w[64];
    #pragma unroll
    for (int k = 0; k < 64; ++k) w[k] = W2[k * 64 + lane];
    float w1l = W1[lane], b1l = b1[lane];
    int beg = rowptr[node], end = rowptr[node + 1];
    float din = dinv[node];
    float partial = 0.f;
    for (int base = beg; base < end; base += 64) {
        int idx = base + lane;
        if (idx < end) {
            int2 p = ep[idx];
            float nrm = dinv[p.x] * __int_as_float(p.y) * din;
            ep[idx] = make_int2(p.x, __float_as_int(nrm));
            partial = fmaf(x[p.x], nrm, partial);
        }
    }
    #pragma unroll
    for (int m = 32; m >= 1; m >>= 1) partial += __shfl_xor(partial, m, 64);
    float sagg = partial + selfn[node] * x[node];
    float v = fmaxf(fmaf(sagg, w1l, b1l), 0.f);
    float u0 = 0.f, u1 = 0.f;
    #pragma unroll
    for (int k = 0; k < 64; k += 2) {
        u0 = fmaf(RLF(v, k),     w[k],     u0);
        u1 = fmaf(RLF(v, k + 1), w[k + 1], u1);
    }
    Gout[node * 64 + lane] = u0 + u1;
}

// Pure aggregation: Y[n] = selfn[n]*G[n] + sum_e nrm_e * G[src_e]
// One wave per node (grid = NN/4); 16 row loads in flight; ep via wave-uniform s_loads.
__global__ __launch_bounds__(256, 4) void k_gather(
    const float* __restrict__ G, const float* __restrict__ selfn,
    const int* __restrict__ rowptr, const int2* __restrict__ ep,
    float* __restrict__ Y)
{
    int lane = threadIdx.x & 63;
    int node = blockIdx.x * 4 + (threadIdx.x >> 6);
    int beg = __builtin_amdgcn_readfirstlane(rowptr[node]);
    int end = __builtin_amdgcn_readfirstlane(rowptr[node + 1]);
    float acc0 = G[node * 64 + lane] * selfn[node];
    float acc1 = 0.f;
    int j = beg;
    for (; j + 16 <= end; j += 16) {
        float h[16], nv[16];
        #pragma unroll
        for (int t = 0; t < 16; ++t) {
            int2 p = ep[j + t];               // uniform address -> scalar load
            h[t]  = G[p.x * 64 + lane];
            nv[t] = __int_as_float(p.y);
        }
        #pragma unroll
        for (int t = 0; t < 16; t += 2) {
            acc0 = fmaf(h[t],     nv[t],     acc0);
            acc1 = fmaf(h[t + 1], nv[t + 1], acc1);
        }
    }
    if (j < end) {                            // masked tail, still batched
        float h[16], nv[16];
        #pragma unroll
        for (int t = 0; t < 16; ++t) {
            int idx = j + t;
            bool valid = idx < end;           // wave-uniform predicate
            int2 p = ep[valid ? idx : j];
            h[t]  = G[p.x * 64 + lane];
            nv[t] = valid ? __int_as_float(p.y) : 0.f;
        }
        #pragma unroll
        for (int t = 0; t < 16; t += 2) {
            acc0 = fmaf(h[t],     nv[t],     acc0);
            acc1 = fmaf(h[t + 1], nv[t + 1], acc1);
        }
    }
    Y[node * 64 + lane] = acc0 + acc1;
}

// H = relu(Y + bias) @ W   — 4 nodes per wave, W held in VGPRs, grid = NN/16
__global__ __launch_bounds__(256, 4) void k_mv(
    const float* __restrict__ Y, const float* __restrict__ bias,
    const float* __restrict__ W, float* __restrict__ H)
{
    int lane = threadIdx.x & 63;
    int wid  = threadIdx.x >> 6;
    float w[64];
    #pragma unroll
    for (int k = 0; k < 64; ++k) w[k] = W[k * 64 + lane];
    float bl = bias[lane];
    int n0 = (blockIdx.x * 4 + wid) * 4;
    float v0 = fmaxf(Y[(n0 + 0) * 64 + lane] + bl, 0.f);
    float v1 = fmaxf(Y[(n0 + 1) * 64 + lane] + bl, 0.f);
    float v2 = fmaxf(Y[(n0 + 2) * 64 + lane] + bl, 0.f);
    float v3 = fmaxf(Y[(n0 + 3) * 64 + lane] + bl, 0.f);
    float a0 = 0.f, a1 = 0.f, a2 = 0.f, a3 = 0.f;
    #pragma unroll
    for (int k = 0; k < 64; ++k) {
        float wk = w[k];
        a0 = fmaf(RLF(v0, k), wk, a0);
        a1 = fmaf(RLF(v1, k), wk, a1);
        a2 = fmaf(RLF(v2, k), wk, a2);
        a3 = fmaf(RLF(v3, k), wk, a3);
    }
    H[(n0 + 0) * 64 + lane] = a0;
    H[(n0 + 1) * 64 + lane] = a1;
    H[(n0 + 2) * 64 + lane] = a2;
    H[(n0 + 3) * 64 + lane] = a3;
}

// out = relu(relu(Y+b5)@fW1 + fb1) @ fW2 + fb2   — 4 nodes per wave, grid = NN/16
__global__ __launch_bounds__(256, 4) void k_head(
    const float* __restrict__ Y, const float* __restrict__ b5,
    const float* __restrict__ fW1, const float* __restrict__ fb1,
    const float* __restrict__ fW2, const float* __restrict__ fb2,
    float* __restrict__ out)
{
    int lane = threadIdx.x & 63;
    int wid  = threadIdx.x >> 6;
    float w[64];
    #pragma unroll
    for (int k = 0; k < 64; ++k) w[k] = fW1[k * 64 + lane];
    float bl = b5[lane], fb1l = fb1[lane], fw2l = fW2[lane], fb2s = fb2[0];
    int n0 = (blockIdx.x * 4 + wid) * 4;
    float v0 = fmaxf(Y[(n0 + 0) * 64 + lane] + bl, 0.f);
    float v1 = fmaxf(Y[(n0 + 1) * 64 + lane] + bl, 0.f);
    float v2 = fmaxf(Y[(n0 + 2) * 64 + lane] + bl, 0.f);
    float v3 = fmaxf(Y[(n0 + 3) * 64 + lane] + bl, 0.f);
    float a0 = 0.f, a1 = 0.f, a2 = 0.f, a3 = 0.f;
    #pragma unroll
    for (int k = 0; k < 64; ++k) {
        float wk = w[k];
        a0 = fmaf(RLF(v0, k), wk, a0);
        a1 = fmaf(RLF(v1, k), wk, a1);
        a2 = fmaf(RLF(v2, k), wk, a2);
        a3 = fmaf(RLF(v3, k), wk, a3);
    }
    float t0 = fmaxf(a0 + fb1l, 0.f) * fw2l;
    float t1 = fmaxf(a1 + fb1l, 0.f) * fw2l;
    float t2 = fmaxf(a2 + fb1l, 0.f) * fw2l;
    float t3 = fmaxf(a3 + fb1l, 0.f) * fw2l;
    #pragma unroll
    for (int m = 32; m >= 1; m >>= 1) {
        t0 += __shfl_xor(t0, m, 64);
        t1 += __shfl_xor(t1, m, 64);
        t2 += __shfl_xor(t2, m, 64);
        t3 += __shfl_xor(t3, m, 64);
    }
    if (lane == 0) {
        out[n0 + 0] = t0 + fb2s;
        out[n0 + 1] = t1 + fb2s;
        out[n0 + 2] = t2 + fb2s;
        out[n0 + 3] = t3 + fb2s;
    }
}

// ---------------- Launch ----------------

extern "C" void kernel_launch(void* const* d_in, const int* in_sizes, int n_in,
                              void* d_out, int out_size, void* d_ws, size_t ws_size,
                              hipStream_t stream) {
    const float* x   = (const float*)d_in[0];
    const int*   ei  = (const int*)d_in[1];
    const float* ew  = (const float*)d_in[2];
    const float* W1  = (const float*)d_in[3];
    const float* b1  = (const float*)d_in[4];
    const float* W2  = (const float*)d_in[5];
    const float* b2  = (const float*)d_in[6];
    const float* W3  = (const float*)d_in[7];
    const float* b3  = (const float*)d_in[8];
    const float* W4  = (const float*)d_in[9];
    const float* b4  = (const float*)d_in[10];
    const float* W5  = (const float*)d_in[11];
    const float* b5  = (const float*)d_in[12];
    const float* fW1 = (const float*)d_in[13];
    const float* fb1 = (const float*)d_in[14];
    const float* fW2 = (const float*)d_in[15];
    const float* fb2 = (const float*)d_in[16];
    float* out = (float*)d_out;

    char* ws = (char*)d_ws;
    size_t o = 0;
    auto alloc = [&](size_t elems) -> void* {
        void* p = (void*)(ws + o);
        o += ((elems * 4 + 255) / 256) * 256;
        return p;
    };
    float* dinv   = (float*)alloc(NN);
    float* selfn  = (float*)alloc(NN);
    int*   rowptr = (int*)alloc(NN + 1);
    int*   cnt    = (int*)alloc(NN);
    int*   bsum   = (int*)alloc(128);
    int*   boff   = (int*)alloc(128);
    int2*  epair  = (int2*)alloc(2 * (size_t)EE);
    float* Yb     = (float*)alloc((size_t)NN * 64);
    float* Ga     = (float*)alloc((size_t)NN * 64);
    float* Gb     = (float*)alloc((size_t)NN * 64);
    int*   slot   = (int*)Yb;   // aliased: slot dead before Yb first written

    int gN  = (NN + 255) / 256;
    int gE  = (EE + 255) / 256;
    int nb  = (NN + 1023) / 1024;    // 98
    int gW1 = NN / 4;                // 25000: 1 node/wave kernels
    int gW4 = NN / 16;               // 6250:  4 nodes/wave kernels

    k_zero<<<gN, 256, 0, stream>>>(cnt);
    k_count<<<gE, 256, 0, stream>>>(ei, cnt, slot);
    k_bsum<<<nb, 256, 0, stream>>>(cnt, bsum);
    k_bscan<<<1, 64, 0, stream>>>(bsum, boff, nb);
    k_scan_out<<<nb, 256, 0, stream>>>(cnt, boff, rowptr);
    k_fill<<<gE, 256, 0, stream>>>(ei, ew, slot, rowptr, epair);
    k_deg<<<gW4, 256, 0, stream>>>(rowptr, epair, dinv, selfn);

    // G2 = relu(Agg(x@W1)+b1) @ W2   (+ inline edge scaling)
    k_fused1<<<gW1, 256, 0, stream>>>(x, dinv, selfn, rowptr, epair, W1, b1, W2, Ga);
    // G3
    k_gather<<<gW1, 256, 0, stream>>>(Ga, selfn, rowptr, epair, Yb);
    k_mv<<<gW4, 256, 0, stream>>>(Yb, b2, W3, Gb);
    // G4
    k_gather<<<gW1, 256, 0, stream>>>(Gb, selfn, rowptr, epair, Yb);
    k_mv<<<gW4, 256, 0, stream>>>(Yb, b3, W4, Ga);
    // G5
    k_gather<<<gW1, 256, 0, stream>>>(Ga, selfn, rowptr, epair, Yb);
    k_mv<<<gW4, 256, 0, stream>>>(Yb, b4, W5, Gb);
    // head
    k_gather<<<gW1, 256, 0, stream>>>(Gb, selfn, rowptr, epair, Yb);
    k_head<<<gW4, 256, 0, stream>>>(Yb, b5, fW1, fb1, fW2, fb2, out);
}

// Round 5
// 551.080 us; speedup vs baseline: 2.0065x; 1.0170x over previous
//
#include <hip/hip_runtime.h>
#include <hip/hip_bf16.h>

#define NN 100000
#define EE 1250000

#define RL(x, l) __builtin_amdgcn_readlane((x), (l))
#define RLF(x, l) __int_as_float(__builtin_amdgcn_readlane(__float_as_int(x), (l)))

// ---------------- CSR build ----------------

// one atomic per edge: slot within dst row
__global__ __launch_bounds__(256) void k_count(const int* __restrict__ ei,
                                               int* __restrict__ cnt,
                                               int* __restrict__ slot) {
    int e = blockIdx.x * 256 + threadIdx.x;
    if (e >= EE) return;
    int d = __builtin_nontemporal_load(&ei[EE + e]);
    slot[e] = atomicAdd(&cnt[d], 1);
}

__global__ __launch_bounds__(256) void k_bsum(const int* __restrict__ cnt, int* __restrict__ bsum) {
    __shared__ int ls[256];
    int b = blockIdx.x, tid = threadIdx.x;
    int base = b * 1024 + tid * 4;
    int s = 0;
    #pragma unroll
    for (int j = 0; j < 4; ++j) { int g = base + j; if (g < NN) s += cnt[g]; }
    ls[tid] = s; __syncthreads();
    for (int off = 128; off > 0; off >>= 1) {
        if (tid < off) ls[tid] += ls[tid + off];
        __syncthreads();
    }
    if (tid == 0) bsum[b] = ls[0];
}

// single-wave scan over nb<=128 block sums
__global__ void k_bscan(const int* __restrict__ bsum, int* __restrict__ boff, int nb) {
    int lane = threadIdx.x & 63;
    int v0 = (lane < nb) ? bsum[lane] : 0;
    int v1 = (64 + lane < nb) ? bsum[64 + lane] : 0;
    int s0 = v0, s1 = v1;
    #pragma unroll
    for (int d = 1; d < 64; d <<= 1) {
        int t0 = __shfl_up(s0, d, 64);
        int t1 = __shfl_up(s1, d, 64);
        if (lane >= d) { s0 += t0; s1 += t1; }
    }
    int tot0 = __shfl(s0, 63, 64);
    s1 += tot0;
    if (lane < nb) boff[lane] = s0 - v0;
    if (64 + lane < nb) boff[64 + lane] = s1 - v1;
}

__global__ __launch_bounds__(256) void k_scan_out(const int* __restrict__ cnt,
                                                  const int* __restrict__ boff,
                                                  int* __restrict__ rowptr) {
    __shared__ int ls[256];
    int b = blockIdx.x, tid = threadIdx.x;
    int base = b * 1024 + tid * 4;
    int c[4]; int s = 0;
    #pragma unroll
    for (int j = 0; j < 4; ++j) {
        int g = base + j;
        c[j] = (g < NN) ? cnt[g] : 0;
        s += c[j];
    }
    ls[tid] = s; __syncthreads();
    for (int off = 1; off < 256; off <<= 1) {
        int v = (tid >= off) ? ls[tid - off] : 0;
        __syncthreads();
        ls[tid] += v;
        __syncthreads();
    }
    int excl = ls[tid] - s + boff[b];
    #pragma unroll
    for (int j = 0; j < 4; ++j) {
        int g = base + j;
        if (g < NN) {
            rowptr[g + 1] = excl + c[j];
            excl += c[j];
        }
    }
    if (b == 0 && tid == 0) rowptr[0] = 0;
}

// atomic-free fill: epair[p] = (src, raw edge weight) — weights stay RAW forever
__global__ __launch_bounds__(256) void k_fill(const int* __restrict__ ei,
                                              const float* __restrict__ ew,
                                              const int* __restrict__ slot,
                                              const int* __restrict__ rowptr,
                                              int2* __restrict__ epair) {
    int e = blockIdx.x * 256 + threadIdx.x;
    if (e >= EE) return;
    int s = __builtin_nontemporal_load(&ei[e]);
    int d = __builtin_nontemporal_load(&ei[EE + e]);
    float w = __builtin_nontemporal_load(&ew[e]);
    int sl = __builtin_nontemporal_load(&slot[e]);
    int p = rowptr[d] + sl;
    epair[p] = make_int2(s, __float_as_int(w));
}

// deg[n] = 1 + sum_row ew -> dinv[n], xd[n] = dinv[n]*x[n].  4 nodes/wave.
__global__ __launch_bounds__(256) void k_deg(const int* __restrict__ rowptr,
                                             const int2* __restrict__ epair,
                                             const float* __restrict__ x,
                                             float* __restrict__ dinv,
                                             float* __restrict__ xd) {
    int lane = threadIdx.x & 63;
    int wid  = threadIdx.x >> 6;
    int l16  = lane & 15;
    int sub  = lane >> 4;
    int node = (blockIdx.x * 4 + wid) * 4 + sub;
    if (node >= NN) return;
    int beg = rowptr[node], end = rowptr[node + 1];
    float s = 0.f;
    for (int idx = beg + l16; idx < end; idx += 16)
        s += __int_as_float(epair[idx].y);
    #pragma unroll
    for (int m = 8; m >= 1; m >>= 1) s += __shfl_xor(s, m, 64);
    if (l16 == 0) {
        float di = rsqrtf(s + 1.0f);
        dinv[node] = di;
        xd[node] = di * x[node];
    }
}

// ---------------- Layers ----------------
// Identity used throughout: Agg_l[d] = dinv_d * ( G'_l[d] + sum_e w_e * G'_l[src] )
// where G'_l = dinv (.) G_l.  epair holds raw w; no edge scaling pass exists.

// Layer-1 scalar aggregation: z[d] = dinv_d * ( xd[d] + sum_e w_e * xd[src] )
__global__ __launch_bounds__(256) void k_gather1(const float* __restrict__ xd,
                                                 const float* __restrict__ dinv,
                                                 const int* __restrict__ rowptr,
                                                 const int2* __restrict__ epair,
                                                 float* __restrict__ z) {
    int lane = threadIdx.x & 63;
    int wid  = threadIdx.x >> 6;
    int l16  = lane & 15;
    int sub  = lane >> 4;
    int node = (blockIdx.x * 4 + wid) * 4 + sub;
    if (node >= NN) return;
    int beg = rowptr[node], end = rowptr[node + 1];
    float partial = 0.f;
    for (int idx = beg + l16; idx < end; idx += 16) {
        int2 p = epair[idx];
        partial = fmaf(__int_as_float(p.y), xd[p.x], partial);
    }
    #pragma unroll
    for (int m = 8; m >= 1; m >>= 1) partial += __shfl_xor(partial, m, 64);
    if (l16 == 0) z[node] = dinv[node] * (xd[node] + partial);
}

// G2' = dinv (.) ( relu(z*W1row + b1) @ W2 )  — 4 nodes/wave, W2 in VGPRs
__global__ __launch_bounds__(256, 4) void k_mv1(
    const float* __restrict__ z, const float* __restrict__ dinv,
    const float* __restrict__ W1, const float* __restrict__ b1,
    const float* __restrict__ W2, float* __restrict__ Gout)
{
    int lane = threadIdx.x & 63;
    int wid  = threadIdx.x >> 6;
    float w[64];
    #pragma unroll
    for (int k = 0; k < 64; ++k) w[k] = W2[k * 64 + lane];
    float w1l = W1[lane], b1l = b1[lane];
    int n0 = (blockIdx.x * 4 + wid) * 4;
    float v0 = fmaxf(fmaf(z[n0 + 0], w1l, b1l), 0.f);
    float v1 = fmaxf(fmaf(z[n0 + 1], w1l, b1l), 0.f);
    float v2 = fmaxf(fmaf(z[n0 + 2], w1l, b1l), 0.f);
    float v3 = fmaxf(fmaf(z[n0 + 3], w1l, b1l), 0.f);
    float a0 = 0.f, a1 = 0.f, a2 = 0.f, a3 = 0.f;
    #pragma unroll
    for (int k = 0; k < 64; ++k) {
        float wk = w[k];
        a0 = fmaf(RLF(v0, k), wk, a0);
        a1 = fmaf(RLF(v1, k), wk, a1);
        a2 = fmaf(RLF(v2, k), wk, a2);
        a3 = fmaf(RLF(v3, k), wk, a3);
    }
    Gout[(n0 + 0) * 64 + lane] = dinv[n0 + 0] * a0;
    Gout[(n0 + 1) * 64 + lane] = dinv[n0 + 1] * a1;
    Gout[(n0 + 2) * 64 + lane] = dinv[n0 + 2] * a2;
    Gout[(n0 + 3) * 64 + lane] = dinv[n0 + 3] * a3;
}

// Aggregation: Y[d] = dinv_d * ( G'[d] + sum_e w_e * G'[src] )
// One wave per node; 16 row loads in flight; epair via wave-uniform s_loads.
__global__ __launch_bounds__(256, 4) void k_gather(
    const float* __restrict__ G, const float* __restrict__ dinv,
    const int* __restrict__ rowptr, const int2* __restrict__ ep,
    float* __restrict__ Y)
{
    int lane = threadIdx.x & 63;
    int node = blockIdx.x * 4 + (threadIdx.x >> 6);
    int beg = __builtin_amdgcn_readfirstlane(rowptr[node]);
    int end = __builtin_amdgcn_readfirstlane(rowptr[node + 1]);
    float acc0 = G[node * 64 + lane];
    float acc1 = 0.f;
    int j = beg;
    for (; j + 16 <= end; j += 16) {
        float h[16], nv[16];
        #pragma unroll
        for (int t = 0; t < 16; ++t) {
            int2 p = ep[j + t];               // uniform address -> scalar load
            h[t]  = G[p.x * 64 + lane];
            nv[t] = __int_as_float(p.y);
        }
        #pragma unroll
        for (int t = 0; t < 16; t += 2) {
            acc0 = fmaf(h[t],     nv[t],     acc0);
            acc1 = fmaf(h[t + 1], nv[t + 1], acc1);
        }
    }
    if (j < end) {                            // masked tail, still batched
        float h[16], nv[16];
        #pragma unroll
        for (int t = 0; t < 16; ++t) {
            int idx = j + t;
            bool valid = idx < end;           // wave-uniform predicate
            int2 p = ep[valid ? idx : j];
            h[t]  = G[p.x * 64 + lane];
            nv[t] = valid ? __int_as_float(p.y) : 0.f;
        }
        #pragma unroll
        for (int t = 0; t < 16; t += 2) {
            acc0 = fmaf(h[t],     nv[t],     acc0);
            acc1 = fmaf(h[t + 1], nv[t + 1], acc1);
        }
    }
    Y[node * 64 + lane] = dinv[node] * (acc0 + acc1);
}

// H' = dinv (.) ( relu(Y + bias) @ W )  — 4 nodes/wave, W in VGPRs
__global__ __launch_bounds__(256, 4) void k_mv(
    const float* __restrict__ Y, const float* __restrict__ dinv,
    const float* __restrict__ bias, const float* __restrict__ W,
    float* __restrict__ H)
{
    int lane = threadIdx.x & 63;
    int wid  = threadIdx.x >> 6;
    float w[64];
    #pragma unroll
    for (int k = 0; k < 64; ++k) w[k] = W[k * 64 + lane];
    float bl = bias[lane];
    int n0 = (blockIdx.x * 4 + wid) * 4;
    float v0 = fmaxf(Y[(n0 + 0) * 64 + lane] + bl, 0.f);
    float v1 = fmaxf(Y[(n0 + 1) * 64 + lane] + bl, 0.f);
    float v2 = fmaxf(Y[(n0 + 2) * 64 + lane] + bl, 0.f);
    float v3 = fmaxf(Y[(n0 + 3) * 64 + lane] + bl, 0.f);
    float a0 = 0.f, a1 = 0.f, a2 = 0.f, a3 = 0.f;
    #pragma unroll
    for (int k = 0; k < 64; ++k) {
        float wk = w[k];
        a0 = fmaf(RLF(v0, k), wk, a0);
        a1 = fmaf(RLF(v1, k), wk, a1);
        a2 = fmaf(RLF(v2, k), wk, a2);
        a3 = fmaf(RLF(v3, k), wk, a3);
    }
    H[(n0 + 0) * 64 + lane] = dinv[n0 + 0] * a0;
    H[(n0 + 1) * 64 + lane] = dinv[n0 + 1] * a1;
    H[(n0 + 2) * 64 + lane] = dinv[n0 + 2] * a2;
    H[(n0 + 3) * 64 + lane] = dinv[n0 + 3] * a3;
}

// out = relu(relu(Y+b5)@fW1 + fb1) @ fW2 + fb2   — 4 nodes/wave
__global__ __launch_bounds__(256, 4) void k_head(
    const float* __restrict__ Y, const float* __restrict__ b5,
    const float* __restrict__ fW1, const float* __restrict__ fb1,
    const float* __restrict__ fW2, const float* __restrict__ fb2,
    float* __restrict__ out)
{
    int lane = threadIdx.x & 63;
    int wid  = threadIdx.x >> 6;
    float w[64];
    #pragma unroll
    for (int k = 0; k < 64; ++k) w[k] = fW1[k * 64 + lane];
    float bl = b5[lane], fb1l = fb1[lane], fw2l = fW2[lane], fb2s = fb2[0];
    int n0 = (blockIdx.x * 4 + wid) * 4;
    float v0 = fmaxf(Y[(n0 + 0) * 64 + lane] + bl, 0.f);
    float v1 = fmaxf(Y[(n0 + 1) * 64 + lane] + bl, 0.f);
    float v2 = fmaxf(Y[(n0 + 2) * 64 + lane] + bl, 0.f);
    float v3 = fmaxf(Y[(n0 + 3) * 64 + lane] + bl, 0.f);
    float a0 = 0.f, a1 = 0.f, a2 = 0.f, a3 = 0.f;
    #pragma unroll
    for (int k = 0; k < 64; ++k) {
        float wk = w[k];
        a0 = fmaf(RLF(v0, k), wk, a0);
        a1 = fmaf(RLF(v1, k), wk, a1);
        a2 = fmaf(RLF(v2, k), wk, a2);
        a3 = fmaf(RLF(v3, k), wk, a3);
    }
    float t0 = fmaxf(a0 + fb1l, 0.f) * fw2l;
    float t1 = fmaxf(a1 + fb1l, 0.f) * fw2l;
    float t2 = fmaxf(a2 + fb1l, 0.f) * fw2l;
    float t3 = fmaxf(a3 + fb1l, 0.f) * fw2l;
    #pragma unroll
    for (int m = 32; m >= 1; m >>= 1) {
        t0 += __shfl_xor(t0, m, 64);
        t1 += __shfl_xor(t1, m, 64);
        t2 += __shfl_xor(t2, m, 64);
        t3 += __shfl_xor(t3, m, 64);
    }
    if (lane == 0) {
        out[n0 + 0] = t0 + fb2s;
        out[n0 + 1] = t1 + fb2s;
        out[n0 + 2] = t2 + fb2s;
        out[n0 + 3] = t3 + fb2s;
    }
}

// ---------------- Launch ----------------

extern "C" void kernel_launch(void* const* d_in, const int* in_sizes, int n_in,
                              void* d_out, int out_size, void* d_ws, size_t ws_size,
                              hipStream_t stream) {
    const float* x   = (const float*)d_in[0];
    const int*   ei  = (const int*)d_in[1];
    const float* ew  = (const float*)d_in[2];
    const float* W1  = (const float*)d_in[3];
    const float* b1  = (const float*)d_in[4];
    const float* W2  = (const float*)d_in[5];
    const float* b2  = (const float*)d_in[6];
    const float* W3  = (const float*)d_in[7];
    const float* b3  = (const float*)d_in[8];
    const float* W4  = (const float*)d_in[9];
    const float* b4  = (const float*)d_in[10];
    const float* W5  = (const float*)d_in[11];
    const float* b5  = (const float*)d_in[12];
    const float* fW1 = (const float*)d_in[13];
    const float* fb1 = (const float*)d_in[14];
    const float* fW2 = (const float*)d_in[15];
    const float* fb2 = (const float*)d_in[16];
    float* out = (float*)d_out;

    char* ws = (char*)d_ws;
    size_t o = 0;
    auto alloc = [&](size_t elems) -> void* {
        void* p = (void*)(ws + o);
        o += ((elems * 4 + 255) / 256) * 256;
        return p;
    };
    float* dinv   = (float*)alloc(NN);
    float* xd     = (float*)alloc(NN);
    float* zbuf   = (float*)alloc(NN);
    int*   rowptr = (int*)alloc(NN + 1);
    int*   cnt    = (int*)alloc(NN);
    int*   bsum   = (int*)alloc(128);
    int*   boff   = (int*)alloc(128);
    int2*  epair  = (int2*)alloc(2 * (size_t)EE);
    float* Yb     = (float*)alloc((size_t)NN * 64);
    float* Ga     = (float*)alloc((size_t)NN * 64);
    float* Gb     = (float*)alloc((size_t)NN * 64);
    int*   slot   = (int*)Yb;   // aliased: slot dead before Yb first written

    int gE  = (EE + 255) / 256;
    int nb  = (NN + 1023) / 1024;    // 98
    int gW1 = NN / 4;                // 25000: 1 node/wave kernels
    int gW4 = NN / 16;               // 6250:  4 nodes/wave kernels

    hipMemsetAsync(cnt, 0, NN * sizeof(int), stream);
    k_count<<<gE, 256, 0, stream>>>(ei, cnt, slot);
    k_bsum<<<nb, 256, 0, stream>>>(cnt, bsum);
    k_bscan<<<1, 64, 0, stream>>>(bsum, boff, nb);
    k_scan_out<<<nb, 256, 0, stream>>>(cnt, boff, rowptr);
    k_fill<<<gE, 256, 0, stream>>>(ei, ew, slot, rowptr, epair);
    k_deg<<<gW4, 256, 0, stream>>>(rowptr, epair, x, dinv, xd);

    // Layer 1: scalar aggregation then matvec
    k_gather1<<<gW4, 256, 0, stream>>>(xd, dinv, rowptr, epair, zbuf);
    k_mv1<<<gW4, 256, 0, stream>>>(zbuf, dinv, W1, b1, W2, Ga);
    // Layers 2..4
    k_gather<<<gW1, 256, 0, stream>>>(Ga, dinv, rowptr, epair, Yb);
    k_mv<<<gW4, 256, 0, stream>>>(Yb, dinv, b2, W3, Gb);
    k_gather<<<gW1, 256, 0, stream>>>(Gb, dinv, rowptr, epair, Yb);
    k_mv<<<gW4, 256, 0, stream>>>(Yb, dinv, b3, W4, Ga);
    k_gather<<<gW1, 256, 0, stream>>>(Ga, dinv, rowptr, epair, Yb);
    k_mv<<<gW4, 256, 0, stream>>>(Yb, dinv, b4, W5, Gb);
    // Layer 5 aggregation + MLP head
    k_gather<<<gW1, 256, 0, stream>>>(Gb, dinv, rowptr, epair, Yb);
    k_head<<<gW4, 256, 0, stream>>>(Yb, b5, fW1, fb1, fW2, fb2, out);
}

// Round 6
// 537.115 us; speedup vs baseline: 2.0587x; 1.0260x over previous
//
#include <hip/hip_runtime.h>
#include <hip/hip_bf16.h>

#define NN 100000
#define EE 1250000
#define CSTRIDE 32   // one counter per 128-B line: kills atomic line contention

#define RL(x, l) __builtin_amdgcn_readlane((x), (l))
#define RLF(x, l) __int_as_float(__builtin_amdgcn_readlane(__float_as_int(x), (l)))

// ---------------- CSR build ----------------

// one returning atomic per edge: slot within dst row (cnt padded to 1 line/counter)
__global__ __launch_bounds__(256) void k_count(const int* __restrict__ ei,
                                               int* __restrict__ cnt,
                                               int* __restrict__ slot) {
    int e = blockIdx.x * 256 + threadIdx.x;
    if (e >= EE) return;
    int d = __builtin_nontemporal_load(&ei[EE + e]);
    slot[e] = atomicAdd(&cnt[d * CSTRIDE], 1);
}

__global__ __launch_bounds__(256) void k_bsum(const int* __restrict__ cnt, int* __restrict__ bsum) {
    __shared__ int ls[256];
    int b = blockIdx.x, tid = threadIdx.x;
    int base = b * 1024 + tid * 4;
    int s = 0;
    #pragma unroll
    for (int j = 0; j < 4; ++j) { int g = base + j; if (g < NN) s += cnt[(size_t)g * CSTRIDE]; }
    ls[tid] = s; __syncthreads();
    for (int off = 128; off > 0; off >>= 1) {
        if (tid < off) ls[tid] += ls[tid + off];
        __syncthreads();
    }
    if (tid == 0) bsum[b] = ls[0];
}

// single-wave scan over nb<=128 block sums
__global__ void k_bscan(const int* __restrict__ bsum, int* __restrict__ boff, int nb) {
    int lane = threadIdx.x & 63;
    int v0 = (lane < nb) ? bsum[lane] : 0;
    int v1 = (64 + lane < nb) ? bsum[64 + lane] : 0;
    int s0 = v0, s1 = v1;
    #pragma unroll
    for (int d = 1; d < 64; d <<= 1) {
        int t0 = __shfl_up(s0, d, 64);
        int t1 = __shfl_up(s1, d, 64);
        if (lane >= d) { s0 += t0; s1 += t1; }
    }
    int tot0 = __shfl(s0, 63, 64);
    s1 += tot0;
    if (lane < nb) boff[lane] = s0 - v0;
    if (64 + lane < nb) boff[64 + lane] = s1 - v1;
}

__global__ __launch_bounds__(256) void k_scan_out(const int* __restrict__ cnt,
                                                  const int* __restrict__ boff,
                                                  int* __restrict__ rowptr) {
    __shared__ int ls[256];
    int b = blockIdx.x, tid = threadIdx.x;
    int base = b * 1024 + tid * 4;
    int c[4]; int s = 0;
    #pragma unroll
    for (int j = 0; j < 4; ++j) {
        int g = base + j;
        c[j] = (g < NN) ? cnt[(size_t)g * CSTRIDE] : 0;
        s += c[j];
    }
    ls[tid] = s; __syncthreads();
    for (int off = 1; off < 256; off <<= 1) {
        int v = (tid >= off) ? ls[tid - off] : 0;
        __syncthreads();
        ls[tid] += v;
        __syncthreads();
    }
    int excl = ls[tid] - s + boff[b];
    #pragma unroll
    for (int j = 0; j < 4; ++j) {
        int g = base + j;
        if (g < NN) {
            rowptr[g + 1] = excl + c[j];
            excl += c[j];
        }
    }
    if (b == 0 && tid == 0) rowptr[0] = 0;
}

// atomic-free fill: epair[p] = (src, raw edge weight) — weights stay RAW forever
__global__ __launch_bounds__(256) void k_fill(const int* __restrict__ ei,
                                              const float* __restrict__ ew,
                                              const int* __restrict__ slot,
                                              const int* __restrict__ rowptr,
                                              int2* __restrict__ epair) {
    int e = blockIdx.x * 256 + threadIdx.x;
    if (e >= EE) return;
    int s = __builtin_nontemporal_load(&ei[e]);
    int d = __builtin_nontemporal_load(&ei[EE + e]);
    float w = __builtin_nontemporal_load(&ew[e]);
    int sl = __builtin_nontemporal_load(&slot[e]);
    int p = rowptr[d] + sl;
    epair[p] = make_int2(s, __float_as_int(w));
}

// deg[n] = 1 + sum_row ew -> dinv[n], xd[n] = dinv[n]*x[n].  4 nodes/wave.
__global__ __launch_bounds__(256) void k_deg(const int* __restrict__ rowptr,
                                             const int2* __restrict__ epair,
                                             const float* __restrict__ x,
                                             float* __restrict__ dinv,
                                             float* __restrict__ xd) {
    int lane = threadIdx.x & 63;
    int wid  = threadIdx.x >> 6;
    int l16  = lane & 15;
    int sub  = lane >> 4;
    int node = (blockIdx.x * 4 + wid) * 4 + sub;
    if (node >= NN) return;
    int beg = rowptr[node], end = rowptr[node + 1];
    float s = 0.f;
    for (int idx = beg + l16; idx < end; idx += 16)
        s += __int_as_float(epair[idx].y);
    #pragma unroll
    for (int m = 8; m >= 1; m >>= 1) s += __shfl_xor(s, m, 64);
    if (l16 == 0) {
        float di = rsqrtf(s + 1.0f);
        dinv[node] = di;
        xd[node] = di * x[node];
    }
}

// ---------------- Fused layers ----------------
// Identity: Agg_l[d] = dinv_d * ( G'_l[d] + sum_e w_e * G'_l[src] ), G' = dinv (.) G.
// Matvec fused via LDS-resident W (VGPR w[64] would be demoted — see R2/R4).

// Layer 1: z[d] scalar agg, then G2' = dinv (.) ( relu(z*W1+b1) @ W2 ).
// 4 nodes per wave (16 lanes each for gather); W2 shared via LDS. grid = NN/16.
__global__ __launch_bounds__(256) void k_l1(
    const float* __restrict__ xd, const float* __restrict__ dinv,
    const int* __restrict__ rowptr, const int2* __restrict__ ep,
    const float* __restrict__ W1, const float* __restrict__ b1,
    const float* __restrict__ W2, float* __restrict__ Gout)
{
    __shared__ float sW[4096];
    int tid = threadIdx.x;
    #pragma unroll
    for (int i = 0; i < 16; ++i) sW[tid + i * 256] = W2[tid + i * 256];
    __syncthreads();
    int lane = tid & 63, l16 = lane & 15, sub = lane >> 4;
    int g4 = blockIdx.x * 4 + (tid >> 6);      // node group, 4 nodes
    int nodeS = g4 * 4 + sub;
    int beg = rowptr[nodeS], end = rowptr[nodeS + 1];
    float partial = 0.f;
    for (int idx = beg + l16; idx < end; idx += 16) {
        int2 p = ep[idx];
        partial = fmaf(__int_as_float(p.y), xd[p.x], partial);
    }
    #pragma unroll
    for (int m = 8; m >= 1; m >>= 1) partial += __shfl_xor(partial, m, 64);
    float z = dinv[nodeS] * (xd[nodeS] + partial);   // valid where l16==0
    float z0 = RLF(z, 0), z1 = RLF(z, 16), z2 = RLF(z, 32), z3 = RLF(z, 48);
    float w1l = W1[lane], b1l = b1[lane];
    float v0 = fmaxf(fmaf(z0, w1l, b1l), 0.f);
    float v1 = fmaxf(fmaf(z1, w1l, b1l), 0.f);
    float v2 = fmaxf(fmaf(z2, w1l, b1l), 0.f);
    float v3 = fmaxf(fmaf(z3, w1l, b1l), 0.f);
    float a0 = 0.f, a1 = 0.f, a2 = 0.f, a3 = 0.f;
    #pragma unroll
    for (int k = 0; k < 64; ++k) {
        float wk = sW[k * 64 + lane];
        a0 = fmaf(RLF(v0, k), wk, a0);
        a1 = fmaf(RLF(v1, k), wk, a1);
        a2 = fmaf(RLF(v2, k), wk, a2);
        a3 = fmaf(RLF(v3, k), wk, a3);
    }
    int n0 = g4 * 4;
    Gout[(n0 + 0) * 64 + lane] = dinv[n0 + 0] * a0;
    Gout[(n0 + 1) * 64 + lane] = dinv[n0 + 1] * a1;
    Gout[(n0 + 2) * 64 + lane] = dinv[n0 + 2] * a2;
    Gout[(n0 + 3) * 64 + lane] = dinv[n0 + 3] * a3;
}

// Fused gather + matvec:  Gout' = dinv (.) ( relu( dinv*(agg) + b ) @ W )
// One wave per node, 2 nodes per wave via stride; W in LDS. grid = NN/8 blocks.
__global__ __launch_bounds__(256) void k_glmv(
    const float* __restrict__ G, const float* __restrict__ dinv,
    const int* __restrict__ rowptr, const int2* __restrict__ ep,
    const float* __restrict__ bias, const float* __restrict__ W,
    float* __restrict__ Gout)
{
    __shared__ float sW[4096];
    int tid = threadIdx.x;
    #pragma unroll
    for (int i = 0; i < 16; ++i) sW[tid + i * 256] = W[tid + i * 256];
    __syncthreads();
    int lane = tid & 63;
    float bl = bias[lane];
    int wv = blockIdx.x * 4 + (tid >> 6);          // 0..49999
    for (int node = wv; node < NN; node += 50000) {
        int beg = __builtin_amdgcn_readfirstlane(rowptr[node]);
        int end = __builtin_amdgcn_readfirstlane(rowptr[node + 1]);
        float acc0 = G[node * 64 + lane];
        float acc1 = 0.f;
        int j = beg;
        for (; j + 16 <= end; j += 16) {
            float h[16], nv[16];
            #pragma unroll
            for (int t = 0; t < 16; ++t) {
                int2 p = ep[j + t];               // uniform address -> scalar load
                h[t]  = G[p.x * 64 + lane];
                nv[t] = __int_as_float(p.y);
            }
            #pragma unroll
            for (int t = 0; t < 16; t += 2) {
                acc0 = fmaf(h[t],     nv[t],     acc0);
                acc1 = fmaf(h[t + 1], nv[t + 1], acc1);
            }
        }
        if (j < end) {                            // masked tail, still batched
            float h[16], nv[16];
            #pragma unroll
            for (int t = 0; t < 16; ++t) {
                int idx = j + t;
                bool valid = idx < end;           // wave-uniform predicate
                int2 p = ep[valid ? idx : j];
                h[t]  = G[p.x * 64 + lane];
                nv[t] = valid ? __int_as_float(p.y) : 0.f;
            }
            #pragma unroll
            for (int t = 0; t < 16; t += 2) {
                acc0 = fmaf(h[t],     nv[t],     acc0);
                acc1 = fmaf(h[t + 1], nv[t + 1], acc1);
            }
        }
        float din = dinv[node];
        float v = fmaxf(fmaf(din, acc0 + acc1, bl), 0.f);
        float u0 = 0.f, u1 = 0.f, u2 = 0.f, u3 = 0.f;
        #pragma unroll
        for (int k = 0; k < 64; k += 4) {
            u0 = fmaf(RLF(v, k),     sW[k * 64 + lane],       u0);
            u1 = fmaf(RLF(v, k + 1), sW[(k + 1) * 64 + lane], u1);
            u2 = fmaf(RLF(v, k + 2), sW[(k + 2) * 64 + lane], u2);
            u3 = fmaf(RLF(v, k + 3), sW[(k + 3) * 64 + lane], u3);
        }
        Gout[node * 64 + lane] = din * ((u0 + u1) + (u2 + u3));
    }
}

// Fused gather + MLP head: out = relu(relu(dinv*agg + b5)@fW1 + fb1) @ fW2 + fb2
__global__ __launch_bounds__(256) void k_ghead(
    const float* __restrict__ G, const float* __restrict__ dinv,
    const int* __restrict__ rowptr, const int2* __restrict__ ep,
    const float* __restrict__ b5, const float* __restrict__ fW1,
    const float* __restrict__ fb1, const float* __restrict__ fW2,
    const float* __restrict__ fb2, float* __restrict__ out)
{
    __shared__ float sW[4096];
    __shared__ float sw2[64];
    int tid = threadIdx.x;
    #pragma unroll
    for (int i = 0; i < 16; ++i) sW[tid + i * 256] = fW1[tid + i * 256];
    if (tid < 64) sw2[tid] = fW2[tid];
    __syncthreads();
    int lane = tid & 63;
    float bl = b5[lane], fb1l = fb1[lane], fb2s = fb2[0];
    int wv = blockIdx.x * 4 + (tid >> 6);
    for (int node = wv; node < NN; node += 50000) {
        int beg = __builtin_amdgcn_readfirstlane(rowptr[node]);
        int end = __builtin_amdgcn_readfirstlane(rowptr[node + 1]);
        float acc0 = G[node * 64 + lane];
        float acc1 = 0.f;
        int j = beg;
        for (; j + 16 <= end; j += 16) {
            float h[16], nv[16];
            #pragma unroll
            for (int t = 0; t < 16; ++t) {
                int2 p = ep[j + t];
                h[t]  = G[p.x * 64 + lane];
                nv[t] = __int_as_float(p.y);
            }
            #pragma unroll
            for (int t = 0; t < 16; t += 2) {
                acc0 = fmaf(h[t],     nv[t],     acc0);
                acc1 = fmaf(h[t + 1], nv[t + 1], acc1);
            }
        }
        if (j < end) {
            float h[16], nv[16];
            #pragma unroll
            for (int t = 0; t < 16; ++t) {
                int idx = j + t;
                bool valid = idx < end;
                int2 p = ep[valid ? idx : j];
                h[t]  = G[p.x * 64 + lane];
                nv[t] = valid ? __int_as_float(p.y) : 0.f;
            }
            #pragma unroll
            for (int t = 0; t < 16; t += 2) {
                acc0 = fmaf(h[t],     nv[t],     acc0);
                acc1 = fmaf(h[t + 1], nv[t + 1], acc1);
            }
        }
        float din = dinv[node];
        float v = fmaxf(fmaf(din, acc0 + acc1, bl), 0.f);
        float u0 = 0.f, u1 = 0.f, u2 = 0.f, u3 = 0.f;
        #pragma unroll
        for (int k = 0; k < 64; k += 4) {
            u0 = fmaf(RLF(v, k),     sW[k * 64 + lane],       u0);
            u1 = fmaf(RLF(v, k + 1), sW[(k + 1) * 64 + lane], u1);
            u2 = fmaf(RLF(v, k + 2), sW[(k + 2) * 64 + lane], u2);
            u3 = fmaf(RLF(v, k + 3), sW[(k + 3) * 64 + lane], u3);
        }
        float t0 = fmaxf((u0 + u1) + (u2 + u3) + fb1l, 0.f) * sw2[lane];
        #pragma unroll
        for (int m = 32; m >= 1; m >>= 1) t0 += __shfl_xor(t0, m, 64);
        if (lane == 0) out[node] = t0 + fb2s;
    }
}

// ---------------- Launch ----------------

extern "C" void kernel_launch(void* const* d_in, const int* in_sizes, int n_in,
                              void* d_out, int out_size, void* d_ws, size_t ws_size,
                              hipStream_t stream) {
    const float* x   = (const float*)d_in[0];
    const int*   ei  = (const int*)d_in[1];
    const float* ew  = (const float*)d_in[2];
    const float* W1  = (const float*)d_in[3];
    const float* b1  = (const float*)d_in[4];
    const float* W2  = (const float*)d_in[5];
    const float* b2  = (const float*)d_in[6];
    const float* W3  = (const float*)d_in[7];
    const float* b3  = (const float*)d_in[8];
    const float* W4  = (const float*)d_in[9];
    const float* b4  = (const float*)d_in[10];
    const float* W5  = (const float*)d_in[11];
    const float* b5  = (const float*)d_in[12];
    const float* fW1 = (const float*)d_in[13];
    const float* fb1 = (const float*)d_in[14];
    const float* fW2 = (const float*)d_in[15];
    const float* fb2 = (const float*)d_in[16];
    float* out = (float*)d_out;

    char* ws = (char*)d_ws;
    size_t o = 0;
    auto alloc = [&](size_t elems) -> void* {
        void* p = (void*)(ws + o);
        o += ((elems * 4 + 255) / 256) * 256;
        return p;
    };
    float* dinv   = (float*)alloc(NN);
    float* xd     = (float*)alloc(NN);
    int*   rowptr = (int*)alloc(NN + 1);
    int*   cnt    = (int*)alloc((size_t)NN * CSTRIDE);
    int*   bsum   = (int*)alloc(128);
    int*   boff   = (int*)alloc(128);
    int2*  epair  = (int2*)alloc(2 * (size_t)EE);
    float* Ga     = (float*)alloc((size_t)NN * 64);
    float* Gb     = (float*)alloc((size_t)NN * 64);
    int*   slot   = (int*)Ga;   // aliased: slot dead (after k_fill) before Ga first written (k_l1)

    int gE  = (EE + 255) / 256;
    int nb  = (NN + 1023) / 1024;    // 98
    int gW4 = NN / 16;               // 6250
    int gL  = NN / 8;                // 12500: fused layer kernels, 2 nodes/wave

    hipMemsetAsync(cnt, 0, (size_t)NN * CSTRIDE * sizeof(int), stream);
    k_count<<<gE, 256, 0, stream>>>(ei, cnt, slot);
    k_bsum<<<nb, 256, 0, stream>>>(cnt, bsum);
    k_bscan<<<1, 64, 0, stream>>>(bsum, boff, nb);
    k_scan_out<<<nb, 256, 0, stream>>>(cnt, boff, rowptr);
    k_fill<<<gE, 256, 0, stream>>>(ei, ew, slot, rowptr, epair);
    k_deg<<<gW4, 256, 0, stream>>>(rowptr, epair, x, dinv, xd);

    // Layer 1 (scalar gather + matvec, fused)
    k_l1<<<gW4, 256, 0, stream>>>(xd, dinv, rowptr, epair, W1, b1, W2, Ga);
    // Layers 2..4 (gather + matvec, fused)
    k_glmv<<<gL, 256, 0, stream>>>(Ga, dinv, rowptr, epair, b2, W3, Gb);
    k_glmv<<<gL, 256, 0, stream>>>(Gb, dinv, rowptr, epair, b3, W4, Ga);
    k_glmv<<<gL, 256, 0, stream>>>(Ga, dinv, rowptr, epair, b4, W5, Gb);
    // Layer 5 + MLP head (fused)
    k_ghead<<<gL, 256, 0, stream>>>(Gb, dinv, rowptr, epair, b5, fW1, fb1, fW2, fb2, out);
}

// Round 7
// 509.305 us; speedup vs baseline: 2.1711x; 1.0546x over previous
//
#include <hip/hip_runtime.h>
#include <hip/hip_bf16.h>

#define NN 100000
#define EE 1250000
#define CSTRIDE 32   // one counter per 128-B line: kills atomic line contention

#define RL(x, l) __builtin_amdgcn_readlane((x), (l))
#define RLF(x, l) __int_as_float(__builtin_amdgcn_readlane(__float_as_int(x), (l)))

__device__ __forceinline__ unsigned short bf16rtn(float x) {
    unsigned u = __float_as_uint(x);
    unsigned r = u + 0x7fffu + ((u >> 16) & 1u);
    return (unsigned short)(r >> 16);
}
__device__ __forceinline__ float bflo(unsigned u) { return __uint_as_float(u << 16); }
__device__ __forceinline__ float bfhi(unsigned u) { return __uint_as_float(u & 0xffff0000u); }

// ---------------- CSR build ----------------

__global__ __launch_bounds__(256) void k_count(const int* __restrict__ ei,
                                               int* __restrict__ cnt,
                                               int* __restrict__ slot) {
    int e = blockIdx.x * 256 + threadIdx.x;
    if (e >= EE) return;
    int d = __builtin_nontemporal_load(&ei[EE + e]);
    slot[e] = atomicAdd(&cnt[d * CSTRIDE], 1);
}

__global__ __launch_bounds__(256) void k_bsum(const int* __restrict__ cnt, int* __restrict__ bsum) {
    __shared__ int ls[256];
    int b = blockIdx.x, tid = threadIdx.x;
    int base = b * 1024 + tid * 4;
    int s = 0;
    #pragma unroll
    for (int j = 0; j < 4; ++j) { int g = base + j; if (g < NN) s += cnt[(size_t)g * CSTRIDE]; }
    ls[tid] = s; __syncthreads();
    for (int off = 128; off > 0; off >>= 1) {
        if (tid < off) ls[tid] += ls[tid + off];
        __syncthreads();
    }
    if (tid == 0) bsum[b] = ls[0];
}

__global__ void k_bscan(const int* __restrict__ bsum, int* __restrict__ boff, int nb) {
    int lane = threadIdx.x & 63;
    int v0 = (lane < nb) ? bsum[lane] : 0;
    int v1 = (64 + lane < nb) ? bsum[64 + lane] : 0;
    int s0 = v0, s1 = v1;
    #pragma unroll
    for (int d = 1; d < 64; d <<= 1) {
        int t0 = __shfl_up(s0, d, 64);
        int t1 = __shfl_up(s1, d, 64);
        if (lane >= d) { s0 += t0; s1 += t1; }
    }
    int tot0 = __shfl(s0, 63, 64);
    s1 += tot0;
    if (lane < nb) boff[lane] = s0 - v0;
    if (64 + lane < nb) boff[64 + lane] = s1 - v1;
}

__global__ __launch_bounds__(256) void k_scan_out(const int* __restrict__ cnt,
                                                  const int* __restrict__ boff,
                                                  int* __restrict__ rowptr) {
    __shared__ int ls[256];
    int b = blockIdx.x, tid = threadIdx.x;
    int base = b * 1024 + tid * 4;
    int c[4]; int s = 0;
    #pragma unroll
    for (int j = 0; j < 4; ++j) {
        int g = base + j;
        c[j] = (g < NN) ? cnt[(size_t)g * CSTRIDE] : 0;
        s += c[j];
    }
    ls[tid] = s; __syncthreads();
    for (int off = 1; off < 256; off <<= 1) {
        int v = (tid >= off) ? ls[tid - off] : 0;
        __syncthreads();
        ls[tid] += v;
        __syncthreads();
    }
    int excl = ls[tid] - s + boff[b];
    #pragma unroll
    for (int j = 0; j < 4; ++j) {
        int g = base + j;
        if (g < NN) {
            rowptr[g + 1] = excl + c[j];
            excl += c[j];
        }
    }
    if (b == 0 && tid == 0) rowptr[0] = 0;
}

__global__ __launch_bounds__(256) void k_fill(const int* __restrict__ ei,
                                              const float* __restrict__ ew,
                                              const int* __restrict__ slot,
                                              const int* __restrict__ rowptr,
                                              int2* __restrict__ epair) {
    int e = blockIdx.x * 256 + threadIdx.x;
    if (e >= EE) return;
    int s = __builtin_nontemporal_load(&ei[e]);
    int d = __builtin_nontemporal_load(&ei[EE + e]);
    float w = __builtin_nontemporal_load(&ew[e]);
    int sl = __builtin_nontemporal_load(&slot[e]);
    int p = rowptr[d] + sl;
    epair[p] = make_int2(s, __float_as_int(w));
}

// deg[n] = 1 + sum_row ew -> dinv[n], xd[n] = dinv[n]*x[n].  4 nodes/wave.
__global__ __launch_bounds__(256) void k_deg(const int* __restrict__ rowptr,
                                             const int2* __restrict__ epair,
                                             const float* __restrict__ x,
                                             float* __restrict__ dinv,
                                             float* __restrict__ xd) {
    int lane = threadIdx.x & 63;
    int wid  = threadIdx.x >> 6;
    int l16  = lane & 15;
    int sub  = lane >> 4;
    int node = (blockIdx.x * 4 + wid) * 4 + sub;
    if (node >= NN) return;
    int beg = rowptr[node], end = rowptr[node + 1];
    float s = 0.f;
    for (int idx = beg + l16; idx < end; idx += 16)
        s += __int_as_float(epair[idx].y);
    #pragma unroll
    for (int m = 8; m >= 1; m >>= 1) s += __shfl_xor(s, m, 64);
    if (l16 == 0) {
        float di = rsqrtf(s + 1.0f);
        dinv[node] = di;
        xd[node] = di * x[node];
    }
}

// ---------------- Layers ----------------
// Identity: Agg_l[d] = dinv_d * ( G'_l[d] + sum_e w_e * G'_l[src] ), G' = dinv (.) G.
// G' stored in bf16 (64 feats = 32 uints/row). Y and all accumulation fp32.

// Layer 1: z scalar agg + matvec, W2 via LDS (amortized over 4 nodes/wave). grid NN/16.
__global__ __launch_bounds__(256) void k_l1(
    const float* __restrict__ xd, const float* __restrict__ dinv,
    const int* __restrict__ rowptr, const int2* __restrict__ ep,
    const float* __restrict__ W1, const float* __restrict__ b1,
    const float* __restrict__ W2, unsigned short* __restrict__ Gout)
{
    __shared__ float sW[4096];
    int tid = threadIdx.x;
    #pragma unroll
    for (int i = 0; i < 16; ++i) sW[tid + i * 256] = W2[tid + i * 256];
    __syncthreads();
    int lane = tid & 63, l16 = lane & 15, sub = lane >> 4;
    int g4 = blockIdx.x * 4 + (tid >> 6);
    int nodeS = g4 * 4 + sub;
    int beg = rowptr[nodeS], end = rowptr[nodeS + 1];
    float partial = 0.f;
    for (int idx = beg + l16; idx < end; idx += 16) {
        int2 p = ep[idx];
        partial = fmaf(__int_as_float(p.y), xd[p.x], partial);
    }
    #pragma unroll
    for (int m = 8; m >= 1; m >>= 1) partial += __shfl_xor(partial, m, 64);
    float z = dinv[nodeS] * (xd[nodeS] + partial);   // valid where l16==0
    float z0 = RLF(z, 0), z1 = RLF(z, 16), z2 = RLF(z, 32), z3 = RLF(z, 48);
    float w1l = W1[lane], b1l = b1[lane];
    float v0 = fmaxf(fmaf(z0, w1l, b1l), 0.f);
    float v1 = fmaxf(fmaf(z1, w1l, b1l), 0.f);
    float v2 = fmaxf(fmaf(z2, w1l, b1l), 0.f);
    float v3 = fmaxf(fmaf(z3, w1l, b1l), 0.f);
    float a0 = 0.f, a1 = 0.f, a2 = 0.f, a3 = 0.f;
    #pragma unroll
    for (int k = 0; k < 64; ++k) {
        float wk = sW[k * 64 + lane];
        a0 = fmaf(RLF(v0, k), wk, a0);
        a1 = fmaf(RLF(v1, k), wk, a1);
        a2 = fmaf(RLF(v2, k), wk, a2);
        a3 = fmaf(RLF(v3, k), wk, a3);
    }
    int n0 = g4 * 4;
    Gout[(n0 + 0) * 64 + lane] = bf16rtn(dinv[n0 + 0] * a0);
    Gout[(n0 + 1) * 64 + lane] = bf16rtn(dinv[n0 + 1] * a1);
    Gout[(n0 + 2) * 64 + lane] = bf16rtn(dinv[n0 + 2] * a2);
    Gout[(n0 + 3) * 64 + lane] = bf16rtn(dinv[n0 + 3] * a3);
}

// Gather over bf16 rows: Y[d] = dinv_d * ( G'[d] + sum_e w_e * G'[src] ).
// One wave per node; 2 edges per row-load (halves of the wave), 8 loads in flight;
// ep reads stay wave-uniform (s_load) with cndmask half-select. grid = NN/4.
__global__ __launch_bounds__(256) void k_gather(
    const unsigned* __restrict__ G16, const float* __restrict__ dinv,
    const int* __restrict__ rowptr, const int2* __restrict__ ep,
    float* __restrict__ Y)
{
    int tid = threadIdx.x;
    int lane = tid & 63;
    int lc = lane & 31;
    int half = lane >> 5;
    int node = blockIdx.x * 4 + (tid >> 6);
    int beg = __builtin_amdgcn_readfirstlane(rowptr[node]);
    int end = __builtin_amdgcn_readfirstlane(rowptr[node + 1]);
    float ax = 0.f, ay = 0.f;
    if (half == 0) {
        unsigned u = G16[node * 32 + lc];
        ax = bflo(u); ay = bfhi(u);
    }
    int j = beg;
    for (; j + 16 <= end; j += 16) {          // full batch: 16 edges, 8 loads
        unsigned u[8]; float nv[8];
        #pragma unroll
        for (int t = 0; t < 8; ++t) {
            int2 pa = ep[j + t];              // uniform -> s_load
            int2 pb = ep[j + 8 + t];          // uniform -> s_load
            int src = half ? pb.x : pa.x;
            nv[t] = __int_as_float(half ? pb.y : pa.y);
            u[t] = G16[src * 32 + lc];
        }
        #pragma unroll
        for (int t = 0; t < 8; ++t) {
            ax = fmaf(bflo(u[t]), nv[t], ax);
            ay = fmaf(bfhi(u[t]), nv[t], ay);
        }
    }
    if (j < end) {                            // masked batch
        unsigned u[8]; float nv[8];
        #pragma unroll
        for (int t = 0; t < 8; ++t) {
            int ia = j + t, ib = j + 8 + t;   // uniform
            int2 pa = ep[ia < end ? ia : j];
            int2 pb = ep[ib < end ? ib : j];
            bool va = ia < end, vb = ib < end;
            int src = half ? pb.x : pa.x;
            float w = __int_as_float(half ? pb.y : pa.y);
            bool v = half ? vb : va;
            nv[t] = v ? w : 0.f;
            u[t] = G16[src * 32 + lc];
        }
        #pragma unroll
        for (int t = 0; t < 8; ++t) {
            ax = fmaf(bflo(u[t]), nv[t], ax);
            ay = fmaf(bfhi(u[t]), nv[t], ay);
        }
    }
    ax += __shfl_xor(ax, 32, 64);
    ay += __shfl_xor(ay, 32, 64);
    if (half == 0) {
        float din = dinv[node];
        float2 o = make_float2(din * ax, din * ay);
        *((float2*)(Y + (size_t)node * 64) + lc) = o;
    }
}

// G' = dinv (.) ( relu(Y + bias) @ W ), bf16 out — 4 nodes/wave, W in VGPRs. grid NN/16.
__global__ __launch_bounds__(256, 4) void k_mv(
    const float* __restrict__ Y, const float* __restrict__ dinv,
    const float* __restrict__ bias, const float* __restrict__ W,
    unsigned short* __restrict__ Gout)
{
    int lane = threadIdx.x & 63;
    int wid  = threadIdx.x >> 6;
    float w[64];
    #pragma unroll
    for (int k = 0; k < 64; ++k) w[k] = W[k * 64 + lane];
    float bl = bias[lane];
    int n0 = (blockIdx.x * 4 + wid) * 4;
    float v0 = fmaxf(Y[(n0 + 0) * 64 + lane] + bl, 0.f);
    float v1 = fmaxf(Y[(n0 + 1) * 64 + lane] + bl, 0.f);
    float v2 = fmaxf(Y[(n0 + 2) * 64 + lane] + bl, 0.f);
    float v3 = fmaxf(Y[(n0 + 3) * 64 + lane] + bl, 0.f);
    float a0 = 0.f, a1 = 0.f, a2 = 0.f, a3 = 0.f;
    #pragma unroll
    for (int k = 0; k < 64; ++k) {
        float wk = w[k];
        a0 = fmaf(RLF(v0, k), wk, a0);
        a1 = fmaf(RLF(v1, k), wk, a1);
        a2 = fmaf(RLF(v2, k), wk, a2);
        a3 = fmaf(RLF(v3, k), wk, a3);
    }
    Gout[(n0 + 0) * 64 + lane] = bf16rtn(dinv[n0 + 0] * a0);
    Gout[(n0 + 1) * 64 + lane] = bf16rtn(dinv[n0 + 1] * a1);
    Gout[(n0 + 2) * 64 + lane] = bf16rtn(dinv[n0 + 2] * a2);
    Gout[(n0 + 3) * 64 + lane] = bf16rtn(dinv[n0 + 3] * a3);
}

// out = relu(relu(Y+b5)@fW1 + fb1) @ fW2 + fb2 — 4 nodes/wave, fW1 in VGPRs. grid NN/16.
__global__ __launch_bounds__(256, 4) void k_head(
    const float* __restrict__ Y, const float* __restrict__ b5,
    const float* __restrict__ fW1, const float* __restrict__ fb1,
    const float* __restrict__ fW2, const float* __restrict__ fb2,
    float* __restrict__ out)
{
    int lane = threadIdx.x & 63;
    int wid  = threadIdx.x >> 6;
    float w[64];
    #pragma unroll
    for (int k = 0; k < 64; ++k) w[k] = fW1[k * 64 + lane];
    float bl = b5[lane], fb1l = fb1[lane], fw2l = fW2[lane], fb2s = fb2[0];
    int n0 = (blockIdx.x * 4 + wid) * 4;
    float v0 = fmaxf(Y[(n0 + 0) * 64 + lane] + bl, 0.f);
    float v1 = fmaxf(Y[(n0 + 1) * 64 + lane] + bl, 0.f);
    float v2 = fmaxf(Y[(n0 + 2) * 64 + lane] + bl, 0.f);
    float v3 = fmaxf(Y[(n0 + 3) * 64 + lane] + bl, 0.f);
    float a0 = 0.f, a1 = 0.f, a2 = 0.f, a3 = 0.f;
    #pragma unroll
    for (int k = 0; k < 64; ++k) {
        float wk = w[k];
        a0 = fmaf(RLF(v0, k), wk, a0);
        a1 = fmaf(RLF(v1, k), wk, a1);
        a2 = fmaf(RLF(v2, k), wk, a2);
        a3 = fmaf(RLF(v3, k), wk, a3);
    }
    float t0 = fmaxf(a0 + fb1l, 0.f) * fw2l;
    float t1 = fmaxf(a1 + fb1l, 0.f) * fw2l;
    float t2 = fmaxf(a2 + fb1l, 0.f) * fw2l;
    float t3 = fmaxf(a3 + fb1l, 0.f) * fw2l;
    #pragma unroll
    for (int m = 32; m >= 1; m >>= 1) {
        t0 += __shfl_xor(t0, m, 64);
        t1 += __shfl_xor(t1, m, 64);
        t2 += __shfl_xor(t2, m, 64);
        t3 += __shfl_xor(t3, m, 64);
    }
    if (lane == 0) {
        out[n0 + 0] = t0 + fb2s;
        out[n0 + 1] = t1 + fb2s;
        out[n0 + 2] = t2 + fb2s;
        out[n0 + 3] = t3 + fb2s;
    }
}

// ---------------- Launch ----------------

extern "C" void kernel_launch(void* const* d_in, const int* in_sizes, int n_in,
                              void* d_out, int out_size, void* d_ws, size_t ws_size,
                              hipStream_t stream) {
    const float* x   = (const float*)d_in[0];
    const int*   ei  = (const int*)d_in[1];
    const float* ew  = (const float*)d_in[2];
    const float* W1  = (const float*)d_in[3];
    const float* b1  = (const float*)d_in[4];
    const float* W2  = (const float*)d_in[5];
    const float* b2  = (const float*)d_in[6];
    const float* W3  = (const float*)d_in[7];
    const float* b3  = (const float*)d_in[8];
    const float* W4  = (const float*)d_in[9];
    const float* b4  = (const float*)d_in[10];
    const float* W5  = (const float*)d_in[11];
    const float* b5  = (const float*)d_in[12];
    const float* fW1 = (const float*)d_in[13];
    const float* fb1 = (const float*)d_in[14];
    const float* fW2 = (const float*)d_in[15];
    const float* fb2 = (const float*)d_in[16];
    float* out = (float*)d_out;

    char* ws = (char*)d_ws;
    size_t o = 0;
    auto alloc = [&](size_t elems) -> void* {
        void* p = (void*)(ws + o);
        o += ((elems * 4 + 255) / 256) * 256;
        return p;
    };
    float* dinv   = (float*)alloc(NN);
    float* xd     = (float*)alloc(NN);
    int*   rowptr = (int*)alloc(NN + 1);
    int*   cnt    = (int*)alloc((size_t)NN * CSTRIDE);
    int*   bsum   = (int*)alloc(128);
    int*   boff   = (int*)alloc(128);
    int2*  epair  = (int2*)alloc(2 * (size_t)EE);
    float* Yb     = (float*)alloc((size_t)NN * 64);       // fp32 gather output
    unsigned* Ga16 = (unsigned*)alloc((size_t)NN * 32);   // bf16 feature rows
    unsigned* Gb16 = (unsigned*)alloc((size_t)NN * 32);
    int*   slot   = (int*)Yb;   // aliased: slot dead (after k_fill) before Yb first written

    int gE  = (EE + 255) / 256;
    int nb  = (NN + 1023) / 1024;    // 98
    int gW1 = NN / 4;                // 25000: 1 node/wave
    int gW4 = NN / 16;               // 6250:  4 nodes/wave

    hipMemsetAsync(cnt, 0, (size_t)NN * CSTRIDE * sizeof(int), stream);
    k_count<<<gE, 256, 0, stream>>>(ei, cnt, slot);
    k_bsum<<<nb, 256, 0, stream>>>(cnt, bsum);
    k_bscan<<<1, 64, 0, stream>>>(bsum, boff, nb);
    k_scan_out<<<nb, 256, 0, stream>>>(cnt, boff, rowptr);
    k_fill<<<gE, 256, 0, stream>>>(ei, ew, slot, rowptr, epair);
    k_deg<<<gW4, 256, 0, stream>>>(rowptr, epair, x, dinv, xd);

    // Layer 1 (scalar gather + matvec) -> G2' bf16
    k_l1<<<gW4, 256, 0, stream>>>(xd, dinv, rowptr, epair, W1, b1, W2,
                                  (unsigned short*)Ga16);
    // Layers 2..4
    k_gather<<<gW1, 256, 0, stream>>>(Ga16, dinv, rowptr, epair, Yb);
    k_mv<<<gW4, 256, 0, stream>>>(Yb, dinv, b2, W3, (unsigned short*)Gb16);
    k_gather<<<gW1, 256, 0, stream>>>(Gb16, dinv, rowptr, epair, Yb);
    k_mv<<<gW4, 256, 0, stream>>>(Yb, dinv, b3, W4, (unsigned short*)Ga16);
    k_gather<<<gW1, 256, 0, stream>>>(Ga16, dinv, rowptr, epair, Yb);
    k_mv<<<gW4, 256, 0, stream>>>(Yb, dinv, b4, W5, (unsigned short*)Gb16);
    // Layer 5 + head
    k_gather<<<gW1, 256, 0, stream>>>(Gb16, dinv, rowptr, epair, Yb);
    k_head<<<gW4, 256, 0, stream>>>(Yb, b5, fW1, fb1, fW2, fb2, out);
}